// Round 5
// baseline (2283.663 us; speedup 1.0000x reference)
//
#include <hip/hip_runtime.h>

#define DEVI __device__ __forceinline__

typedef unsigned short u16;
typedef __attribute__((ext_vector_type(8))) _Float16 f16x8;
typedef __attribute__((ext_vector_type(4))) float f32x4;

#define NQ   2048
#define DIMM 1024
#define HD   16
#define MM   16
#define JTOT 2064   // MM + NC
#define JPK  2080   // padded kn rows (65*32)
#define JPAD 2112   // padded j stride (66*32)
#define KTOP 64

DEVI u16 f2h(float x) {
    _Float16 h = (_Float16)x;
    u16 r; __builtin_memcpy(&r, &h, 2); return r;
}
DEVI void fsplit(float x, u16& hi, u16& lo) {
    _Float16 h = (_Float16)x;
    float r = x - (float)h;
    _Float16 l = (_Float16)r;
    __builtin_memcpy(&hi, &h, 2);
    __builtin_memcpy(&lo, &l, 2);
}

// ---------------- split-cast a f32 tensor to (hi, lo) f16 pair --------------
__global__ __launch_bounds__(256) void split1_kernel(
    const float* __restrict__ s, u16* __restrict__ hi, u16* __restrict__ lo, int n4)
{
    int gid = blockIdx.x * 256 + threadIdx.x;
    if (gid < n4) {
        float4 v = ((const float4*)s)[gid];
        ushort4 h, l;
        fsplit(v.x, h.x, l.x); fsplit(v.y, h.y, l.y);
        fsplit(v.z, h.z, l.z); fsplit(v.w, h.w, l.w);
        ((ushort4*)hi)[gid] = h;
        ((ushort4*)lo)[gid] = l;
    }
}

// ---------------- transpose + split-cast the 8 weight matrices --------------
struct P8 { const float* w[8]; };

__global__ __launch_bounds__(256) void wtrans_kernel(P8 src, u16* WTh, u16* WTl) {
    __shared__ float T[64][65];
    const float* W = src.w[blockIdx.z];
    size_t off = (size_t)blockIdx.z * DIMM * DIMM;
    int n0 = blockIdx.x * 64, k0 = blockIdx.y * 64;
#pragma unroll
    for (int rep = 0; rep < 16; ++rep) {
        int idx = rep * 256 + threadIdx.x;
        int kk = idx >> 6, nn = idx & 63;
        T[kk][nn] = W[(size_t)(k0 + kk) * DIMM + n0 + nn];
    }
    __syncthreads();
#pragma unroll
    for (int rep = 0; rep < 16; ++rep) {
        int idx = rep * 256 + threadIdx.x;
        int nn = idx >> 6, kk = idx & 63;
        u16 h, l; fsplit(T[kk][nn], h, l);
        WTh[off + (size_t)(n0 + nn) * DIMM + k0 + kk] = h;
        WTl[off + (size_t)(n0 + nn) * DIMM + k0 + kk] = l;
    }
}

// ------- plain NT f16 MFMA GEMM  C[M,N] = A[M,K] * B[N,K]^T (batched) -------
// OM 0: f32 out, 1: f16 out.
template<int OM>
__global__ __launch_bounds__(256) void gemm_nt(
    const u16* __restrict__ A, int lda, long sA,
    const u16* __restrict__ B, int ldb, long sB,
    void* __restrict__ Cv, int ldc, long sC, int K)
{
    __shared__ u16 As[64 * 40];
    __shared__ u16 Bs[64 * 40];
    const int tid = threadIdx.x;
    const int z = blockIdx.z;
    A += (size_t)z * sA; B += (size_t)z * sB;
    const int bm = blockIdx.x * 64, bn = blockIdx.y * 64;
    const int l = tid & 63, w = tid >> 6;
    const int wm = (w >> 1) * 32, wn = (w & 1) * 32;
    const int srow = tid >> 2, skcol = (tid & 3) * 8;
    const u16* Ag = A + (size_t)(bm + srow) * lda + skcol;
    const u16* Bg = B + (size_t)(bn + srow) * ldb + skcol;
    const int lr = l & 15, lk = (l >> 4) * 8;
    f32x4 acc[2][2] = {};
    for (int k0 = 0; k0 < K; k0 += 32) {
        uint4 av = *(const uint4*)(Ag + k0);
        uint4 bv = *(const uint4*)(Bg + k0);
        __syncthreads();
        *(uint4*)&As[srow * 40 + skcol] = av;
        *(uint4*)&Bs[srow * 40 + skcol] = bv;
        __syncthreads();
        f16x8 a0 = *(const f16x8*)&As[(wm + lr) * 40 + lk];
        f16x8 a1 = *(const f16x8*)&As[(wm + 16 + lr) * 40 + lk];
        f16x8 b0 = *(const f16x8*)&Bs[(wn + lr) * 40 + lk];
        f16x8 b1 = *(const f16x8*)&Bs[(wn + 16 + lr) * 40 + lk];
        acc[0][0] = __builtin_amdgcn_mfma_f32_16x16x32_f16(a0, b0, acc[0][0], 0, 0, 0);
        acc[0][1] = __builtin_amdgcn_mfma_f32_16x16x32_f16(a0, b1, acc[0][1], 0, 0, 0);
        acc[1][0] = __builtin_amdgcn_mfma_f32_16x16x32_f16(a1, b0, acc[1][0], 0, 0, 0);
        acc[1][1] = __builtin_amdgcn_mfma_f32_16x16x32_f16(a1, b1, acc[1][1], 0, 0, 0);
    }
    const int crow0 = bm + wm + (l >> 4) * 4;
    const int ccol0 = bn + wn + lr;
#pragma unroll
    for (int mi = 0; mi < 2; ++mi)
#pragma unroll
        for (int ni = 0; ni < 2; ++ni)
#pragma unroll
            for (int r = 0; r < 4; ++r) {
                int row = crow0 + mi * 16 + r;
                int col = ccol0 + ni * 16;
                if (OM == 0) {
                    float* C = (float*)Cv + (size_t)z * sC;
                    C[(size_t)row * ldc + col] = acc[mi][ni][r];
                } else {
                    u16* C = (u16*)Cv + (size_t)z * sC;
                    C[(size_t)row * ldc + col] = f2h(acc[mi][ni][r]);
                }
            }
}

// ---- split-f16 3-term NT GEMM: C = (Ah+Al)(Bh+Bl)^T, f32 out (z=1) --------
__global__ __launch_bounds__(256) void gemm3_nt(
    const u16* __restrict__ Ah, const u16* __restrict__ Al, int lda,
    const u16* __restrict__ Bh, const u16* __restrict__ Bl, int ldb,
    float* __restrict__ C, int ldc, int K)
{
    __shared__ u16 Ash[64 * 40];
    __shared__ u16 Asl[64 * 40];
    __shared__ u16 Bsh[64 * 40];
    __shared__ u16 Bsl[64 * 40];
    const int tid = threadIdx.x;
    const int bm = blockIdx.x * 64, bn = blockIdx.y * 64;
    const int l = tid & 63, w = tid >> 6;
    const int wm = (w >> 1) * 32, wn = (w & 1) * 32;
    const int srow = tid >> 2, skcol = (tid & 3) * 8;
    const size_t aoff = (size_t)(bm + srow) * lda + skcol;
    const size_t boff = (size_t)(bn + srow) * ldb + skcol;
    const int lr = l & 15, lk = (l >> 4) * 8;
    f32x4 acc[2][2] = {};
    for (int k0 = 0; k0 < K; k0 += 32) {
        uint4 avh = *(const uint4*)(Ah + aoff + k0);
        uint4 avl = *(const uint4*)(Al + aoff + k0);
        uint4 bvh = *(const uint4*)(Bh + boff + k0);
        uint4 bvl = *(const uint4*)(Bl + boff + k0);
        __syncthreads();
        *(uint4*)&Ash[srow * 40 + skcol] = avh;
        *(uint4*)&Asl[srow * 40 + skcol] = avl;
        *(uint4*)&Bsh[srow * 40 + skcol] = bvh;
        *(uint4*)&Bsl[srow * 40 + skcol] = bvl;
        __syncthreads();
        f16x8 a0h = *(const f16x8*)&Ash[(wm + lr) * 40 + lk];
        f16x8 a1h = *(const f16x8*)&Ash[(wm + 16 + lr) * 40 + lk];
        f16x8 a0l = *(const f16x8*)&Asl[(wm + lr) * 40 + lk];
        f16x8 a1l = *(const f16x8*)&Asl[(wm + 16 + lr) * 40 + lk];
        f16x8 b0h = *(const f16x8*)&Bsh[(wn + lr) * 40 + lk];
        f16x8 b1h = *(const f16x8*)&Bsh[(wn + 16 + lr) * 40 + lk];
        f16x8 b0l = *(const f16x8*)&Bsl[(wn + lr) * 40 + lk];
        f16x8 b1l = *(const f16x8*)&Bsl[(wn + 16 + lr) * 40 + lk];
#define MF(acc_, a_, b_) acc_ = __builtin_amdgcn_mfma_f32_16x16x32_f16(a_, b_, acc_, 0, 0, 0)
        MF(acc[0][0], a0h, b0h); MF(acc[0][0], a0h, b0l); MF(acc[0][0], a0l, b0h);
        MF(acc[0][1], a0h, b1h); MF(acc[0][1], a0h, b1l); MF(acc[0][1], a0l, b1h);
        MF(acc[1][0], a1h, b0h); MF(acc[1][0], a1h, b0l); MF(acc[1][0], a1l, b0h);
        MF(acc[1][1], a1h, b1h); MF(acc[1][1], a1h, b1l); MF(acc[1][1], a1l, b1h);
#undef MF
    }
    const int crow0 = bm + wm + (l >> 4) * 4;
    const int ccol0 = bn + wn + lr;
#pragma unroll
    for (int mi = 0; mi < 2; ++mi)
#pragma unroll
        for (int ni = 0; ni < 2; ++ni)
#pragma unroll
            for (int r = 0; r < 4; ++r)
                C[(size_t)(crow0 + mi * 16 + r) * ldc + ccol0 + ni * 16] = acc[mi][ni][r];
}

// ------- normalize Q (fold per-head scale), write split f16 [h][i][64] ------
__global__ __launch_bounds__(256) void normq_kernel(
    const float* __restrict__ Qf, const float* __restrict__ scp,
    u16* __restrict__ qnh, u16* __restrict__ qnl)
{
    int w = threadIdx.x >> 6, l = threadIdx.x & 63;
    int wid = blockIdx.x * 4 + w;        // [0, 16*2048)
    int h = wid >> 11, i = wid & 2047;
    float x = Qf[(size_t)i * DIMM + h * 64 + l];
    float ss = x * x;
#pragma unroll
    for (int m = 32; m; m >>= 1) ss += __shfl_xor(ss, m);
    float inv = 1.0f / fmaxf(sqrtf(ss), 1e-12f);
    float sc = 1.0f / fmaxf(expf(scp[h]), 0.01f);
    u16 hh, ll; fsplit(x * inv * sc, hh, ll);
    size_t idx = ((size_t)h * NQ + i) * 64 + l;
    qnh[idx] = hh; qnl[idx] = ll;
}

// ------- build normalized K (mem-prepend + zero pad), split f16 -------------
__global__ __launch_bounds__(256) void buildkn_kernel(
    const float* __restrict__ Kf, const float* __restrict__ mem_k,
    u16* __restrict__ knh, u16* __restrict__ knl)
{
    int w = threadIdx.x >> 6, l = threadIdx.x & 63;
    int wid = blockIdx.x * 4 + w;        // [0, 16*2080)
    int h = wid / JPK, j = wid - h * JPK;
    float x = (j < MM) ? mem_k[((size_t)h * MM + j) * 64 + l]
            : (j < JTOT) ? Kf[(size_t)(j - MM) * DIMM + h * 64 + l] : 0.0f;
    float ss = x * x;
#pragma unroll
    for (int m = 32; m; m >>= 1) ss += __shfl_xor(ss, m);
    float inv = 1.0f / fmaxf(sqrtf(ss), 1e-12f);
    u16 hh, ll; fsplit(x * inv, hh, ll);
    size_t idx = ((size_t)h * JPK + j) * 64 + l;
    knh[idx] = hh; knl[idx] = ll;
}

// ---------------- build V^T (mem-prepend, head_scale folded), f16 ----------
__global__ __launch_bounds__(256) void buildvvT_kernel(
    const float* __restrict__ Vf, const float* __restrict__ mem_v,
    const float* __restrict__ hsp, u16* __restrict__ vvT)
{
    __shared__ float T[64][65];
    int h = blockIdx.z, j0 = blockIdx.x * 64;
    float hs = hsp[h];
#pragma unroll
    for (int rep = 0; rep < 16; ++rep) {
        int idx = rep * 256 + threadIdx.x;
        int jl = idx >> 6, d = idx & 63;
        int j = j0 + jl;
        float x = (j < MM) ? mem_v[((size_t)h * MM + j) * 64 + d]
                : (j < JTOT) ? Vf[(size_t)(j - MM) * DIMM + h * 64 + d] : 0.0f;
        T[jl][d] = x * hs;
    }
    __syncthreads();
#pragma unroll
    for (int rep = 0; rep < 16; ++rep) {
        int idx = rep * 256 + threadIdx.x;
        int d = idx >> 6, jl = idx & 63;
        vvT[((size_t)h * 64 + d) * JPAD + j0 + jl] = f2h(T[jl][d]);
    }
}

// ------- fused per-head QK^T (split-f16) + th_pre mix, h split over waves ---
__global__ __launch_bounds__(256) void dots_kernel(
    const u16* __restrict__ qnh, const u16* __restrict__ qnl,
    const u16* __restrict__ knh, const u16* __restrict__ knl,
    const float* __restrict__ th_pre, float* __restrict__ D,
    int q0, int NQC)
{
    __shared__ float red[4][8][256];   // 32 KB
    const int tid = threadIdx.x, l = tid & 63, w = tid >> 6;
    const int it = blockIdx.x * 16;
    const int jt = blockIdx.y * 16;
    const int lr = l & 15, lk = (l >> 4) * 8;
    const int qrow = q0 + it + lr;
    const int jrow = jt + lr;
    f32x4 accg[16] = {};
#pragma unroll
    for (int hh = 0; hh < 4; ++hh) {
        const int h = w * 4 + hh;
        size_t qo = (((size_t)h * NQ + qrow) << 6) + lk;
        size_t ko = (((size_t)h * JPK + jrow) << 6) + lk;
        const f16x8* pah = (const f16x8*)(qnh + qo);
        const f16x8* pal = (const f16x8*)(qnl + qo);
        const f16x8* pbh = (const f16x8*)(knh + ko);
        const f16x8* pbl = (const f16x8*)(knl + ko);
        f16x8 a0h = pah[0], a1h = pah[4];
        f16x8 a0l = pal[0], a1l = pal[4];
        f16x8 b0h = pbh[0], b1h = pbh[4];
        f16x8 b0l = pbl[0], b1l = pbl[4];
        f32x4 ah = {};
        ah = __builtin_amdgcn_mfma_f32_16x16x32_f16(a0h, b0h, ah, 0, 0, 0);
        ah = __builtin_amdgcn_mfma_f32_16x16x32_f16(a1h, b1h, ah, 0, 0, 0);
        ah = __builtin_amdgcn_mfma_f32_16x16x32_f16(a0h, b0l, ah, 0, 0, 0);
        ah = __builtin_amdgcn_mfma_f32_16x16x32_f16(a1h, b1l, ah, 0, 0, 0);
        ah = __builtin_amdgcn_mfma_f32_16x16x32_f16(a0l, b0h, ah, 0, 0, 0);
        ah = __builtin_amdgcn_mfma_f32_16x16x32_f16(a1l, b1h, ah, 0, 0, 0);
#pragma unroll
        for (int g = 0; g < 16; ++g)
            accg[g] += th_pre[g * 16 + h] * ah;
    }
    const int orow = it + (l >> 4) * 4;
    const int col = jt + lr;
#pragma unroll
    for (int ph = 0; ph < 2; ++ph) {
        __syncthreads();
#pragma unroll
        for (int g = 0; g < 8; ++g)
            *(f32x4*)&red[w][g][l * 4] = accg[ph * 8 + g];
        __syncthreads();
#pragma unroll
        for (int gq = 0; gq < 2; ++gq) {
            const int gl = w * 2 + gq;
            f32x4 s = *(const f32x4*)&red[0][gl][l * 4];
            s += *(const f32x4*)&red[1][gl][l * 4];
            s += *(const f32x4*)&red[2][gl][l * 4];
            s += *(const f32x4*)&red[3][gl][l * 4];
            const int g = ph * 8 + gl;
#pragma unroll
            for (int r = 0; r < 4; ++r)
                D[((size_t)g * NQC + orow + r) * JPAD + col] = s[r];
        }
    }
}

// ---- FUSED: exact top-k stats (radix) + thresholded softmax + MFMA th_post
// ---- mix. One block per query row i; 4 waves. Phase A: wave w computes
// ---- stats for h=4w..4w+3 (rows read global, register radix). Phase B: all
// ---- waves sweep 16-j tiles; mix over h via one mfma_f32_16x16x32_f16
// ---- (A = th_post zero-padded K=32). D re-reads hit same-XCD L2.
__global__ __launch_bounds__(256) void smfused_kernel(
    const float* __restrict__ D, const float* __restrict__ th_post,
    u16* __restrict__ P, int NQC)
{
    __shared__ float s_kth[16], s_mx[16], s_inv[16];
    const int tid = threadIdx.x, l = tid & 63, w = tid >> 6;
    const int i = blockIdx.x;
    const size_t plane = (size_t)NQC * JPAD;
    // -------- phase A: stats for 4 rows --------
    for (int hh = 0; hh < 4; ++hh) {
        const int h = w * 4 + hh;
        const float* Dr = D + (size_t)h * plane + (size_t)i * JPAD;
        float v[33]; unsigned ku[33];
#pragma unroll
        for (int s = 0; s < 33; ++s) {
            int j = s * 64 + l;
            float x = (j < JTOT) ? Dr[j] : -3.0e38f;
            v[s] = x;
            unsigned u = __float_as_uint(x);
            ku[s] = (j < JTOT) ? ((u & 0x80000000u) ? ~u : (u | 0x80000000u)) : 0u;
        }
        unsigned t = 0;
        for (int b = 31; b >= 0; --b) {
            unsigned tc = t | (1u << b);
            int c = 0;
#pragma unroll
            for (int s = 0; s < 33; ++s) c += (ku[s] >= tc);
#pragma unroll
            for (int m = 32; m; m >>= 1) c += __shfl_xor(c, m);
            if (c >= KTOP) t = tc;
        }
        float mx = v[0];
#pragma unroll
        for (int s = 1; s < 33; ++s) mx = fmaxf(mx, v[s]);
#pragma unroll
        for (int m = 32; m; m >>= 1) mx = fmaxf(mx, __shfl_xor(mx, m));
        float den = 0.0f;
#pragma unroll
        for (int s = 0; s < 33; ++s) den += (ku[s] >= t) ? __expf(v[s] - mx) : 0.0f;
#pragma unroll
        for (int m = 32; m; m >>= 1) den += __shfl_xor(den, m);
        if (l == 0) {
            float kth = (t & 0x80000000u) ? __uint_as_float(t ^ 0x80000000u)
                                          : __uint_as_float(~t);
            s_kth[h] = kth; s_mx[h] = mx; s_inv[h] = 1.0f / den;
        }
    }
    __syncthreads();
    // -------- phase B: MFMA th_post mix --------
    const int g = l & 15, hg = l >> 4;
    const int hb = (hg & 1) * 8;          // B-frag k rows 0..7 / 8..15 (dup'd)
    f16x8 afr;
#pragma unroll
    for (int idx = 0; idx < 8; ++idx) {
        int k = hg * 8 + idx;
        float av = (k < 16) ? th_post[g * 16 + k] : 0.0f;
        afr[idx] = (_Float16)av;
    }
    float kthv[8], mxv[8], invv[8];
#pragma unroll
    for (int idx = 0; idx < 8; ++idx) {
        kthv[idx] = s_kth[hb + idx];
        mxv[idx]  = s_mx[hb + idx];
        invv[idx] = s_inv[hb + idx];
    }
    const float* Dbase = D + (size_t)i * JPAD;
    for (int t = w; t < 129; t += 4) {
        const int j = t * 16 + (l & 15);
        f16x8 bfr;
#pragma unroll
        for (int idx = 0; idx < 8; ++idx) {
            float d = Dbase[(size_t)(hb + idx) * plane + j];
            float e = (d >= kthv[idx]) ? __expf(d - mxv[idx]) * invv[idx] : 0.0f;
            bfr[idx] = (_Float16)e;
        }
        f32x4 c = {};
        c = __builtin_amdgcn_mfma_f32_16x16x32_f16(afr, bfr, c, 0, 0, 0);
#pragma unroll
        for (int r = 0; r < 4; ++r) {
            const int gg = hg * 4 + r;
            P[(size_t)gg * plane + (size_t)i * JPAD + j] = f2h(c[r]);
        }
    }
}

// ============================================================================
extern "C" void kernel_launch(void* const* d_in, const int* in_sizes, int n_in,
                              void* d_out, int out_size, void* d_ws, size_t ws_size,
                              hipStream_t stream)
{
    (void)in_sizes; (void)n_in; (void)out_size;
    const float* x      = (const float*)d_in[0];
    const float* ctx    = (const float*)d_in[1];
    const float* Wq1    = (const float*)d_in[4];
    const float* Wk1    = (const float*)d_in[5];
    const float* Wv1    = (const float*)d_in[6];
    const float* Wq2    = (const float*)d_in[7];
    const float* Wk2    = (const float*)d_in[8];
    const float* Wv2    = (const float*)d_in[9];
    const float* thpre1 = (const float*)d_in[10];
    const float* thpost1= (const float*)d_in[11];
    const float* thpre2 = (const float*)d_in[12];
    const float* thpost2= (const float*)d_in[13];
    const float* memk1  = (const float*)d_in[14];
    const float* memv1  = (const float*)d_in[15];
    const float* memk2  = (const float*)d_in[16];
    const float* memv2  = (const float*)d_in[17];
    const float* sc1    = (const float*)d_in[18];
    const float* sc2    = (const float*)d_in[19];
    const float* hs1    = (const float*)d_in[20];
    const float* hs2    = (const float*)d_in[21];
    const float* Wo1    = (const float*)d_in[22];
    const float* Wo2    = (const float*)d_in[23];

    char* p = (char*)d_ws;
    auto alloc = [&](size_t n) { char* r = p; p += (n + 255) & ~(size_t)255; return r; };
    u16*   xbh   = (u16*)alloc((size_t)NQ * DIMM * 2);
    u16*   xbl   = (u16*)alloc((size_t)NQ * DIMM * 2);
    u16*   cb0h  = (u16*)alloc((size_t)NQ * DIMM * 2);
    u16*   cb0l  = (u16*)alloc((size_t)NQ * DIMM * 2);
    u16*   cb1h  = (u16*)alloc((size_t)NQ * DIMM * 2);
    u16*   cb1l  = (u16*)alloc((size_t)NQ * DIMM * 2);
    u16*   WTh   = (u16*)alloc((size_t)8 * DIMM * DIMM * 2);
    u16*   WTl   = (u16*)alloc((size_t)8 * DIMM * DIMM * 2);
    float* Qf    = (float*)alloc((size_t)NQ * DIMM * 4);   // also reused as x2f
    float* Kf    = (float*)alloc((size_t)NQ * DIMM * 4);
    float* Vf    = (float*)alloc((size_t)NQ * DIMM * 4);
    u16*   qnh   = (u16*)alloc((size_t)16 * NQ * 64 * 2);
    u16*   qnl   = (u16*)alloc((size_t)16 * NQ * 64 * 2);
    u16*   knh   = (u16*)alloc((size_t)16 * JPK * 64 * 2);
    u16*   knl   = (u16*)alloc((size_t)16 * JPK * 64 * 2);
    u16*   vvT   = (u16*)alloc((size_t)16 * 64 * JPAD * 2);
    u16*   attnA = (u16*)alloc((size_t)NQ * DIMM * 2);
    size_t used = (size_t)(p - (char*)d_ws);

    int NQC = 32;
    for (int cand : {512, 256, 128, 64}) {
        if (used + (size_t)16 * cand * JPAD * 6 + 1024 <= ws_size) { NQC = cand; break; }
    }
    float* Dbuf = (float*)alloc((size_t)16 * NQC * JPAD * 4);
    u16*   Pbuf = (u16*)alloc((size_t)16 * NQC * JPAD * 2);

    // ---- one-time split-casts ----
    const int N4 = (NQ * DIMM) / 4;
    split1_kernel<<<2048, 256, 0, stream>>>(x, xbh, xbl, N4);
    split1_kernel<<<2048, 256, 0, stream>>>(ctx, cb0h, cb0l, N4);
    split1_kernel<<<2048, 256, 0, stream>>>(ctx + (size_t)NQ * DIMM, cb1h, cb1l, N4);
    P8 w8{ { Wq1, Wk1, Wv1, Wo1, Wq2, Wk2, Wv2, Wo2 } };
    wtrans_kernel<<<dim3(16, 16, 8), 256, 0, stream>>>(w8, WTh, WTl);

    auto layer = [&](const u16* inh, const u16* inl,
                     const u16* ctxh, const u16* ctxl, int wbase,
                     const float* thpre, const float* thpost,
                     const float* memk, const float* memv,
                     const float* scp, const float* hsp, int li) {
        size_t o_q = (size_t)(wbase + 0) * DIMM * DIMM;
        size_t o_k = (size_t)(wbase + 1) * DIMM * DIMM;
        size_t o_v = (size_t)(wbase + 2) * DIMM * DIMM;
        size_t o_o = (size_t)(wbase + 3) * DIMM * DIMM;
        gemm3_nt<<<dim3(32, 16), 256, 0, stream>>>(inh, inl, DIMM, WTh + o_q, WTl + o_q, DIMM, Qf, DIMM, DIMM);
        gemm3_nt<<<dim3(32, 16), 256, 0, stream>>>(ctxh, ctxl, DIMM, WTh + o_k, WTl + o_k, DIMM, Kf, DIMM, DIMM);
        gemm_nt<0><<<dim3(32, 16, 1), 256, 0, stream>>>(ctxh, DIMM, 0, WTh + o_v, DIMM, 0, Vf, DIMM, 0, DIMM);
        normq_kernel<<<(16 * NQ) / 4, 256, 0, stream>>>(Qf, scp, qnh, qnl);
        buildkn_kernel<<<(16 * JPK) / 4, 256, 0, stream>>>(Kf, memk, knh, knl);
        buildvvT_kernel<<<dim3(33, 1, 16), 256, 0, stream>>>(Vf, memv, hsp, vvT);
        int nch = NQ / NQC;
        for (int c = 0; c < nch; ++c) {
            int q0 = c * NQC;
            dots_kernel<<<dim3(NQC / 16, JTOT / 16), 256, 0, stream>>>(qnh, qnl, knh, knl, thpre, Dbuf, q0, NQC);
            smfused_kernel<<<NQC, 256, 0, stream>>>(Dbuf, thpost, Pbuf, NQC);
            gemm_nt<1><<<dim3(NQC / 64, 1, 16), 256, 0, stream>>>(
                Pbuf, JPAD, (long)NQC * JPAD, vvT, JPAD, (long)64 * JPAD,
                attnA + (size_t)q0 * DIMM, DIMM, 64, JPAD);
        }
        if (li == 0) {
            // f32 layer-1 output into Qf (dead here), then split for layer 2
            gemm_nt<0><<<dim3(32, 16, 1), 256, 0, stream>>>(attnA, DIMM, 0, WTh + o_o, DIMM, 0, Qf, DIMM, 0, DIMM);
            split1_kernel<<<2048, 256, 0, stream>>>(Qf, xbh, xbl, N4);
        } else {
            gemm_nt<0><<<dim3(32, 16, 1), 256, 0, stream>>>(attnA, DIMM, 0, WTh + o_o, DIMM, 0, d_out, DIMM, 0, DIMM);
        }
    };

    layer(xbh, xbl, cb0h, cb0l, 0, thpre1, thpost1, memk1, memv1, sc1, hs1, 0);
    layer(xbh, xbl, cb1h, cb1l, 4, thpre2, thpost2, memk2, memv2, sc2, hs2, 1);
}

// Round 6
// 1732.291 us; speedup vs baseline: 1.3183x; 1.3183x over previous
//
#include <hip/hip_runtime.h>

#define DEVI __device__ __forceinline__

typedef unsigned short u16;
typedef __attribute__((ext_vector_type(8))) _Float16 f16x8;
typedef __attribute__((ext_vector_type(4))) float f32x4;

#define NQ   2048
#define DIMM 1024
#define HD   16
#define MM   16
#define JTOT 2064   // MM + NC
#define JPK  2080   // padded kn rows (65*32)
#define JPAD 2112   // padded j stride (66*32)
#define KTOP 64

DEVI u16 f2h(float x) {
    _Float16 h = (_Float16)x;
    u16 r; __builtin_memcpy(&r, &h, 2); return r;
}
DEVI void fsplit(float x, u16& hi, u16& lo) {
    _Float16 h = (_Float16)x;
    float r = x - (float)h;
    _Float16 l = (_Float16)r;
    __builtin_memcpy(&hi, &h, 2);
    __builtin_memcpy(&lo, &l, 2);
}

// ---------------- split-cast a f32 tensor to (hi, lo) f16 pair --------------
__global__ __launch_bounds__(256) void split1_kernel(
    const float* __restrict__ s, u16* __restrict__ hi, u16* __restrict__ lo, int n4)
{
    int gid = blockIdx.x * 256 + threadIdx.x;
    if (gid < n4) {
        float4 v = ((const float4*)s)[gid];
        ushort4 h, l;
        fsplit(v.x, h.x, l.x); fsplit(v.y, h.y, l.y);
        fsplit(v.z, h.z, l.z); fsplit(v.w, h.w, l.w);
        ((ushort4*)hi)[gid] = h;
        ((ushort4*)lo)[gid] = l;
    }
}

// ---------------- transpose + split-cast the 8 weight matrices --------------
struct P8 { const float* w[8]; };

__global__ __launch_bounds__(256) void wtrans_kernel(P8 src, u16* WTh, u16* WTl) {
    __shared__ float T[64][65];
    const float* W = src.w[blockIdx.z];
    size_t off = (size_t)blockIdx.z * DIMM * DIMM;
    int n0 = blockIdx.x * 64, k0 = blockIdx.y * 64;
#pragma unroll
    for (int rep = 0; rep < 16; ++rep) {
        int idx = rep * 256 + threadIdx.x;
        int kk = idx >> 6, nn = idx & 63;
        T[kk][nn] = W[(size_t)(k0 + kk) * DIMM + n0 + nn];
    }
    __syncthreads();
#pragma unroll
    for (int rep = 0; rep < 16; ++rep) {
        int idx = rep * 256 + threadIdx.x;
        int nn = idx >> 6, kk = idx & 63;
        u16 h, l; fsplit(T[kk][nn], h, l);
        WTh[off + (size_t)(n0 + nn) * DIMM + k0 + kk] = h;
        WTl[off + (size_t)(n0 + nn) * DIMM + k0 + kk] = l;
    }
}

// ------- plain NT f16 MFMA GEMM  C[M,N] = A[M,K] * B[N,K]^T (batched) -------
// OM 0: f32 out, 1: f16 out.
template<int OM>
__global__ __launch_bounds__(256) void gemm_nt(
    const u16* __restrict__ A, int lda, long sA,
    const u16* __restrict__ B, int ldb, long sB,
    void* __restrict__ Cv, int ldc, long sC, int K)
{
    __shared__ u16 As[64 * 40];
    __shared__ u16 Bs[64 * 40];
    const int tid = threadIdx.x;
    const int z = blockIdx.z;
    A += (size_t)z * sA; B += (size_t)z * sB;
    const int bm = blockIdx.x * 64, bn = blockIdx.y * 64;
    const int l = tid & 63, w = tid >> 6;
    const int wm = (w >> 1) * 32, wn = (w & 1) * 32;
    const int srow = tid >> 2, skcol = (tid & 3) * 8;
    const u16* Ag = A + (size_t)(bm + srow) * lda + skcol;
    const u16* Bg = B + (size_t)(bn + srow) * ldb + skcol;
    const int lr = l & 15, lk = (l >> 4) * 8;
    f32x4 acc[2][2] = {};
    for (int k0 = 0; k0 < K; k0 += 32) {
        uint4 av = *(const uint4*)(Ag + k0);
        uint4 bv = *(const uint4*)(Bg + k0);
        __syncthreads();
        *(uint4*)&As[srow * 40 + skcol] = av;
        *(uint4*)&Bs[srow * 40 + skcol] = bv;
        __syncthreads();
        f16x8 a0 = *(const f16x8*)&As[(wm + lr) * 40 + lk];
        f16x8 a1 = *(const f16x8*)&As[(wm + 16 + lr) * 40 + lk];
        f16x8 b0 = *(const f16x8*)&Bs[(wn + lr) * 40 + lk];
        f16x8 b1 = *(const f16x8*)&Bs[(wn + 16 + lr) * 40 + lk];
        acc[0][0] = __builtin_amdgcn_mfma_f32_16x16x32_f16(a0, b0, acc[0][0], 0, 0, 0);
        acc[0][1] = __builtin_amdgcn_mfma_f32_16x16x32_f16(a0, b1, acc[0][1], 0, 0, 0);
        acc[1][0] = __builtin_amdgcn_mfma_f32_16x16x32_f16(a1, b0, acc[1][0], 0, 0, 0);
        acc[1][1] = __builtin_amdgcn_mfma_f32_16x16x32_f16(a1, b1, acc[1][1], 0, 0, 0);
    }
    const int crow0 = bm + wm + (l >> 4) * 4;
    const int ccol0 = bn + wn + lr;
#pragma unroll
    for (int mi = 0; mi < 2; ++mi)
#pragma unroll
        for (int ni = 0; ni < 2; ++ni)
#pragma unroll
            for (int r = 0; r < 4; ++r) {
                int row = crow0 + mi * 16 + r;
                int col = ccol0 + ni * 16;
                if (OM == 0) {
                    float* C = (float*)Cv + (size_t)z * sC;
                    C[(size_t)row * ldc + col] = acc[mi][ni][r];
                } else {
                    u16* C = (u16*)Cv + (size_t)z * sC;
                    C[(size_t)row * ldc + col] = f2h(acc[mi][ni][r]);
                }
            }
}

// ---- split-f16 3-term NT GEMM: C = (Ah+Al)(Bh+Bl)^T, f32 out (z=1) --------
__global__ __launch_bounds__(256) void gemm3_nt(
    const u16* __restrict__ Ah, const u16* __restrict__ Al, int lda,
    const u16* __restrict__ Bh, const u16* __restrict__ Bl, int ldb,
    float* __restrict__ C, int ldc, int K)
{
    __shared__ u16 Ash[64 * 40];
    __shared__ u16 Asl[64 * 40];
    __shared__ u16 Bsh[64 * 40];
    __shared__ u16 Bsl[64 * 40];
    const int tid = threadIdx.x;
    const int bm = blockIdx.x * 64, bn = blockIdx.y * 64;
    const int l = tid & 63, w = tid >> 6;
    const int wm = (w >> 1) * 32, wn = (w & 1) * 32;
    const int srow = tid >> 2, skcol = (tid & 3) * 8;
    const size_t aoff = (size_t)(bm + srow) * lda + skcol;
    const size_t boff = (size_t)(bn + srow) * ldb + skcol;
    const int lr = l & 15, lk = (l >> 4) * 8;
    f32x4 acc[2][2] = {};
    for (int k0 = 0; k0 < K; k0 += 32) {
        uint4 avh = *(const uint4*)(Ah + aoff + k0);
        uint4 avl = *(const uint4*)(Al + aoff + k0);
        uint4 bvh = *(const uint4*)(Bh + boff + k0);
        uint4 bvl = *(const uint4*)(Bl + boff + k0);
        __syncthreads();
        *(uint4*)&Ash[srow * 40 + skcol] = avh;
        *(uint4*)&Asl[srow * 40 + skcol] = avl;
        *(uint4*)&Bsh[srow * 40 + skcol] = bvh;
        *(uint4*)&Bsl[srow * 40 + skcol] = bvl;
        __syncthreads();
        f16x8 a0h = *(const f16x8*)&Ash[(wm + lr) * 40 + lk];
        f16x8 a1h = *(const f16x8*)&Ash[(wm + 16 + lr) * 40 + lk];
        f16x8 a0l = *(const f16x8*)&Asl[(wm + lr) * 40 + lk];
        f16x8 a1l = *(const f16x8*)&Asl[(wm + 16 + lr) * 40 + lk];
        f16x8 b0h = *(const f16x8*)&Bsh[(wn + lr) * 40 + lk];
        f16x8 b1h = *(const f16x8*)&Bsh[(wn + 16 + lr) * 40 + lk];
        f16x8 b0l = *(const f16x8*)&Bsl[(wn + lr) * 40 + lk];
        f16x8 b1l = *(const f16x8*)&Bsl[(wn + 16 + lr) * 40 + lk];
#define MF(acc_, a_, b_) acc_ = __builtin_amdgcn_mfma_f32_16x16x32_f16(a_, b_, acc_, 0, 0, 0)
        MF(acc[0][0], a0h, b0h); MF(acc[0][0], a0h, b0l); MF(acc[0][0], a0l, b0h);
        MF(acc[0][1], a0h, b1h); MF(acc[0][1], a0h, b1l); MF(acc[0][1], a0l, b1h);
        MF(acc[1][0], a1h, b0h); MF(acc[1][0], a1h, b0l); MF(acc[1][0], a1l, b0h);
        MF(acc[1][1], a1h, b1h); MF(acc[1][1], a1h, b1l); MF(acc[1][1], a1l, b1h);
#undef MF
    }
    const int crow0 = bm + wm + (l >> 4) * 4;
    const int ccol0 = bn + wn + lr;
#pragma unroll
    for (int mi = 0; mi < 2; ++mi)
#pragma unroll
        for (int ni = 0; ni < 2; ++ni)
#pragma unroll
            for (int r = 0; r < 4; ++r)
                C[(size_t)(crow0 + mi * 16 + r) * ldc + ccol0 + ni * 16] = acc[mi][ni][r];
}

// ------- normalize Q (fold per-head scale), write split f16 [h][i][64] ------
__global__ __launch_bounds__(256) void normq_kernel(
    const float* __restrict__ Qf, const float* __restrict__ scp,
    u16* __restrict__ qnh, u16* __restrict__ qnl)
{
    int w = threadIdx.x >> 6, l = threadIdx.x & 63;
    int wid = blockIdx.x * 4 + w;        // [0, 16*2048)
    int h = wid >> 11, i = wid & 2047;
    float x = Qf[(size_t)i * DIMM + h * 64 + l];
    float ss = x * x;
#pragma unroll
    for (int m = 32; m; m >>= 1) ss += __shfl_xor(ss, m);
    float inv = 1.0f / fmaxf(sqrtf(ss), 1e-12f);
    float sc = 1.0f / fmaxf(expf(scp[h]), 0.01f);
    u16 hh, ll; fsplit(x * inv * sc, hh, ll);
    size_t idx = ((size_t)h * NQ + i) * 64 + l;
    qnh[idx] = hh; qnl[idx] = ll;
}

// ------- build normalized K (mem-prepend + zero pad), split f16 -------------
__global__ __launch_bounds__(256) void buildkn_kernel(
    const float* __restrict__ Kf, const float* __restrict__ mem_k,
    u16* __restrict__ knh, u16* __restrict__ knl)
{
    int w = threadIdx.x >> 6, l = threadIdx.x & 63;
    int wid = blockIdx.x * 4 + w;        // [0, 16*2080)
    int h = wid / JPK, j = wid - h * JPK;
    float x = (j < MM) ? mem_k[((size_t)h * MM + j) * 64 + l]
            : (j < JTOT) ? Kf[(size_t)(j - MM) * DIMM + h * 64 + l] : 0.0f;
    float ss = x * x;
#pragma unroll
    for (int m = 32; m; m >>= 1) ss += __shfl_xor(ss, m);
    float inv = 1.0f / fmaxf(sqrtf(ss), 1e-12f);
    u16 hh, ll; fsplit(x * inv, hh, ll);
    size_t idx = ((size_t)h * JPK + j) * 64 + l;
    knh[idx] = hh; knl[idx] = ll;
}

// ---------------- build V^T (mem-prepend, head_scale folded), f16 ----------
__global__ __launch_bounds__(256) void buildvvT_kernel(
    const float* __restrict__ Vf, const float* __restrict__ mem_v,
    const float* __restrict__ hsp, u16* __restrict__ vvT)
{
    __shared__ float T[64][65];
    int h = blockIdx.z, j0 = blockIdx.x * 64;
    float hs = hsp[h];
#pragma unroll
    for (int rep = 0; rep < 16; ++rep) {
        int idx = rep * 256 + threadIdx.x;
        int jl = idx >> 6, d = idx & 63;
        int j = j0 + jl;
        float x = (j < MM) ? mem_v[((size_t)h * MM + j) * 64 + d]
                : (j < JTOT) ? Vf[(size_t)(j - MM) * DIMM + h * 64 + d] : 0.0f;
        T[jl][d] = x * hs;
    }
    __syncthreads();
#pragma unroll
    for (int rep = 0; rep < 16; ++rep) {
        int idx = rep * 256 + threadIdx.x;
        int d = idx >> 6, jl = idx & 63;
        vvT[((size_t)h * 64 + d) * JPAD + j0 + jl] = f2h(T[jl][d]);
    }
}

// ------- fused per-head QK^T (split-f16) + th_pre mix, h split over waves ---
// D layout: [i_local][h][j]  (h stride JPAD, i stride 16*JPAD)
__global__ __launch_bounds__(256) void dots_kernel(
    const u16* __restrict__ qnh, const u16* __restrict__ qnl,
    const u16* __restrict__ knh, const u16* __restrict__ knl,
    const float* __restrict__ th_pre, float* __restrict__ D,
    int q0, int NQC)
{
    __shared__ float red[4][8][256];   // 32 KB
    const int tid = threadIdx.x, l = tid & 63, w = tid >> 6;
    const int it = blockIdx.x * 16;
    const int jt = blockIdx.y * 16;
    const int lr = l & 15, lk = (l >> 4) * 8;
    const int qrow = q0 + it + lr;
    const int jrow = jt + lr;
    f32x4 accg[16] = {};
#pragma unroll
    for (int hh = 0; hh < 4; ++hh) {
        const int h = w * 4 + hh;
        size_t qo = (((size_t)h * NQ + qrow) << 6) + lk;
        size_t ko = (((size_t)h * JPK + jrow) << 6) + lk;
        const f16x8* pah = (const f16x8*)(qnh + qo);
        const f16x8* pal = (const f16x8*)(qnl + qo);
        const f16x8* pbh = (const f16x8*)(knh + ko);
        const f16x8* pbl = (const f16x8*)(knl + ko);
        f16x8 a0h = pah[0], a1h = pah[4];
        f16x8 a0l = pal[0], a1l = pal[4];
        f16x8 b0h = pbh[0], b1h = pbh[4];
        f16x8 b0l = pbl[0], b1l = pbl[4];
        f32x4 ah = {};
        ah = __builtin_amdgcn_mfma_f32_16x16x32_f16(a0h, b0h, ah, 0, 0, 0);
        ah = __builtin_amdgcn_mfma_f32_16x16x32_f16(a1h, b1h, ah, 0, 0, 0);
        ah = __builtin_amdgcn_mfma_f32_16x16x32_f16(a0h, b0l, ah, 0, 0, 0);
        ah = __builtin_amdgcn_mfma_f32_16x16x32_f16(a1h, b1l, ah, 0, 0, 0);
        ah = __builtin_amdgcn_mfma_f32_16x16x32_f16(a0l, b0h, ah, 0, 0, 0);
        ah = __builtin_amdgcn_mfma_f32_16x16x32_f16(a1l, b1h, ah, 0, 0, 0);
#pragma unroll
        for (int g = 0; g < 16; ++g)
            accg[g] += th_pre[g * 16 + h] * ah;
    }
    const int orow = it + (l >> 4) * 4;
    const int col = jt + lr;
#pragma unroll
    for (int ph = 0; ph < 2; ++ph) {
        __syncthreads();
#pragma unroll
        for (int g = 0; g < 8; ++g)
            *(f32x4*)&red[w][g][l * 4] = accg[ph * 8 + g];
        __syncthreads();
#pragma unroll
        for (int gq = 0; gq < 2; ++gq) {
            const int gl = w * 2 + gq;
            f32x4 s = *(const f32x4*)&red[0][gl][l * 4];
            s += *(const f32x4*)&red[1][gl][l * 4];
            s += *(const f32x4*)&red[2][gl][l * 4];
            s += *(const f32x4*)&red[3][gl][l * 4];
            const int g = ph * 8 + gl;
#pragma unroll
            for (int r = 0; r < 4; ++r)
                D[((size_t)(orow + r) * 16 + g) * JPAD + col] = s[r];
        }
    }
}

// ---------------- exact kth-largest (ballot radix) + softmax stats ----------
// row r = i*16 + h maps linearly: Dr = D + r*JPAD  ([i][h][j] layout)
__global__ __launch_bounds__(256) void rowstats_kernel(
    const float* __restrict__ D, float4* __restrict__ stats)
{
    const int w = threadIdx.x >> 6, l = threadIdx.x & 63;
    const int r = blockIdx.x * 4 + w;                 // row in [0, 16*NQC)
    const float* Dr = D + (size_t)r * JPAD;
    float v[33]; unsigned ku[33];
#pragma unroll
    for (int s = 0; s < 33; ++s) {
        int j = s * 64 + l;
        float x = (j < JTOT) ? Dr[j] : -3.0e38f;
        v[s] = x;
        unsigned u = __float_as_uint(x);
        ku[s] = (j < JTOT) ? ((u & 0x80000000u) ? ~u : (u | 0x80000000u)) : 0u;
    }
    unsigned t = 0;
    for (int b = 31; b >= 0; --b) {
        unsigned tc = t | (1u << b);
        int c = 0;
#pragma unroll
        for (int s = 0; s < 33; ++s)
            c += (int)__popcll(__ballot(ku[s] >= tc));
        if (c >= KTOP) t = tc;
    }
    float mx = v[0];
#pragma unroll
    for (int s = 1; s < 33; ++s) mx = fmaxf(mx, v[s]);
#pragma unroll
    for (int m = 32; m; m >>= 1) mx = fmaxf(mx, __shfl_xor(mx, m));
    float den = 0.0f;
#pragma unroll
    for (int s = 0; s < 33; ++s) den += (ku[s] >= t) ? __expf(v[s] - mx) : 0.0f;
#pragma unroll
    for (int m = 32; m; m >>= 1) den += __shfl_xor(den, m);
    if (l == 0) {
        float kth = (t & 0x80000000u) ? __uint_as_float(t ^ 0x80000000u)
                                      : __uint_as_float(~t);
        stats[r] = make_float4(kth, mx, 1.0f / den, 0.0f);
    }
}

// ---------------- thresholded softmax + th_post head-mix, write f16 P ------
// D,P layout: [i][h][j]; 16 h-slices of one i span 135 KB (L2-local).
__global__ __launch_bounds__(256) void probsmix_kernel(
    const float* __restrict__ D, const float4* __restrict__ stats,
    const float* __restrict__ th_post, u16* __restrict__ P, int NQC)
{
    int gid = blockIdx.x * 256 + threadIdx.x;
    int i = gid / 528;
    int jj = (gid - i * 528) * 4;
    f32x4 pm[16] = {};
    if (jj < JTOT) {
#pragma unroll
        for (int h = 0; h < 16; ++h) {
            float4 x = *(const float4*)(D + ((size_t)i * 16 + h) * JPAD + jj);
            float4 s = stats[i * 16 + h];
            f32x4 p;
            p[0] = (x.x >= s.x) ? __expf(x.x - s.y) * s.z : 0.0f;
            p[1] = (x.y >= s.x) ? __expf(x.y - s.y) * s.z : 0.0f;
            p[2] = (x.z >= s.x) ? __expf(x.z - s.y) * s.z : 0.0f;
            p[3] = (x.w >= s.x) ? __expf(x.w - s.y) * s.z : 0.0f;
#pragma unroll
            for (int g = 0; g < 16; ++g)
                pm[g] += th_post[g * 16 + h] * p;
        }
    }
#pragma unroll
    for (int g = 0; g < 16; ++g) {
        ushort4 o;
        o.x = f2h(pm[g][0]); o.y = f2h(pm[g][1]);
        o.z = f2h(pm[g][2]); o.w = f2h(pm[g][3]);
        *(ushort4*)(P + ((size_t)i * 16 + g) * JPAD + jj) = o;
    }
}

// ============================================================================
extern "C" void kernel_launch(void* const* d_in, const int* in_sizes, int n_in,
                              void* d_out, int out_size, void* d_ws, size_t ws_size,
                              hipStream_t stream)
{
    (void)in_sizes; (void)n_in; (void)out_size;
    const float* x      = (const float*)d_in[0];
    const float* ctx    = (const float*)d_in[1];
    const float* Wq1    = (const float*)d_in[4];
    const float* Wk1    = (const float*)d_in[5];
    const float* Wv1    = (const float*)d_in[6];
    const float* Wq2    = (const float*)d_in[7];
    const float* Wk2    = (const float*)d_in[8];
    const float* Wv2    = (const float*)d_in[9];
    const float* thpre1 = (const float*)d_in[10];
    const float* thpost1= (const float*)d_in[11];
    const float* thpre2 = (const float*)d_in[12];
    const float* thpost2= (const float*)d_in[13];
    const float* memk1  = (const float*)d_in[14];
    const float* memv1  = (const float*)d_in[15];
    const float* memk2  = (const float*)d_in[16];
    const float* memv2  = (const float*)d_in[17];
    const float* sc1    = (const float*)d_in[18];
    const float* sc2    = (const float*)d_in[19];
    const float* hs1    = (const float*)d_in[20];
    const float* hs2    = (const float*)d_in[21];
    const float* Wo1    = (const float*)d_in[22];
    const float* Wo2    = (const float*)d_in[23];

    char* p = (char*)d_ws;
    auto alloc = [&](size_t n) { char* r = p; p += (n + 255) & ~(size_t)255; return r; };
    u16*   xbh   = (u16*)alloc((size_t)NQ * DIMM * 2);
    u16*   xbl   = (u16*)alloc((size_t)NQ * DIMM * 2);
    u16*   cb0h  = (u16*)alloc((size_t)NQ * DIMM * 2);
    u16*   cb0l  = (u16*)alloc((size_t)NQ * DIMM * 2);
    u16*   cb1h  = (u16*)alloc((size_t)NQ * DIMM * 2);
    u16*   cb1l  = (u16*)alloc((size_t)NQ * DIMM * 2);
    u16*   WTh   = (u16*)alloc((size_t)8 * DIMM * DIMM * 2);
    u16*   WTl   = (u16*)alloc((size_t)8 * DIMM * DIMM * 2);
    float* Qf    = (float*)alloc((size_t)NQ * DIMM * 4);   // also reused as x2f
    float* Kf    = (float*)alloc((size_t)NQ * DIMM * 4);
    float* Vf    = (float*)alloc((size_t)NQ * DIMM * 4);
    u16*   qnh   = (u16*)alloc((size_t)16 * NQ * 64 * 2);
    u16*   qnl   = (u16*)alloc((size_t)16 * NQ * 64 * 2);
    u16*   knh   = (u16*)alloc((size_t)16 * JPK * 64 * 2);
    u16*   knl   = (u16*)alloc((size_t)16 * JPK * 64 * 2);
    u16*   vvT   = (u16*)alloc((size_t)16 * 64 * JPAD * 2);
    u16*   attnA = (u16*)alloc((size_t)NQ * DIMM * 2);
    float4* stats = (float4*)alloc((size_t)16 * NQ * 16);
    size_t used = (size_t)(p - (char*)d_ws);

    int NQC = 32;
    for (int cand : {512, 256, 128, 64}) {
        if (used + (size_t)16 * cand * JPAD * 6 + 1024 <= ws_size) { NQC = cand; break; }
    }
    float* Dbuf = (float*)alloc((size_t)16 * NQC * JPAD * 4);
    u16*   Pbuf = (u16*)alloc((size_t)16 * NQC * JPAD * 2);

    // ---- one-time split-casts ----
    const int N4 = (NQ * DIMM) / 4;
    split1_kernel<<<2048, 256, 0, stream>>>(x, xbh, xbl, N4);
    split1_kernel<<<2048, 256, 0, stream>>>(ctx, cb0h, cb0l, N4);
    split1_kernel<<<2048, 256, 0, stream>>>(ctx + (size_t)NQ * DIMM, cb1h, cb1l, N4);
    P8 w8{ { Wq1, Wk1, Wv1, Wo1, Wq2, Wk2, Wv2, Wo2 } };
    wtrans_kernel<<<dim3(16, 16, 8), 256, 0, stream>>>(w8, WTh, WTl);

    auto layer = [&](const u16* inh, const u16* inl,
                     const u16* ctxh, const u16* ctxl, int wbase,
                     const float* thpre, const float* thpost,
                     const float* memk, const float* memv,
                     const float* scp, const float* hsp, int li) {
        size_t o_q = (size_t)(wbase + 0) * DIMM * DIMM;
        size_t o_k = (size_t)(wbase + 1) * DIMM * DIMM;
        size_t o_v = (size_t)(wbase + 2) * DIMM * DIMM;
        size_t o_o = (size_t)(wbase + 3) * DIMM * DIMM;
        gemm3_nt<<<dim3(32, 16), 256, 0, stream>>>(inh, inl, DIMM, WTh + o_q, WTl + o_q, DIMM, Qf, DIMM, DIMM);
        gemm3_nt<<<dim3(32, 16), 256, 0, stream>>>(ctxh, ctxl, DIMM, WTh + o_k, WTl + o_k, DIMM, Kf, DIMM, DIMM);
        gemm_nt<0><<<dim3(32, 16, 1), 256, 0, stream>>>(ctxh, DIMM, 0, WTh + o_v, DIMM, 0, Vf, DIMM, 0, DIMM);
        normq_kernel<<<(16 * NQ) / 4, 256, 0, stream>>>(Qf, scp, qnh, qnl);
        buildkn_kernel<<<(16 * JPK) / 4, 256, 0, stream>>>(Kf, memk, knh, knl);
        buildvvT_kernel<<<dim3(33, 1, 16), 256, 0, stream>>>(Vf, memv, hsp, vvT);
        int nch = NQ / NQC;
        for (int c = 0; c < nch; ++c) {
            int q0 = c * NQC;
            dots_kernel<<<dim3(NQC / 16, JTOT / 16), 256, 0, stream>>>(qnh, qnl, knh, knl, thpre, Dbuf, q0, NQC);
            rowstats_kernel<<<(16 * NQC) / 4, 256, 0, stream>>>(Dbuf, stats);
            probsmix_kernel<<<(NQC * 528) / 256, 256, 0, stream>>>(Dbuf, stats, thpost, Pbuf, NQC);
            gemm_nt<1><<<dim3(NQC / 64, 1, 16), 256, 0, stream>>>(
                Pbuf, 16 * JPAD, (long)JPAD, vvT, JPAD, (long)64 * JPAD,
                attnA + (size_t)q0 * DIMM, DIMM, 64, JPAD);
        }
        if (li == 0) {
            // f32 layer-1 output into Qf (dead here), then split for layer 2
            gemm_nt<0><<<dim3(32, 16, 1), 256, 0, stream>>>(attnA, DIMM, 0, WTh + o_o, DIMM, 0, Qf, DIMM, 0, DIMM);
            split1_kernel<<<2048, 256, 0, stream>>>(Qf, xbh, xbl, N4);
        } else {
            gemm_nt<0><<<dim3(32, 16, 1), 256, 0, stream>>>(attnA, DIMM, 0, WTh + o_o, DIMM, 0, d_out, DIMM, 0, DIMM);
        }
    };

    layer(xbh, xbl, cb0h, cb0l, 0, thpre1, thpost1, memk1, memv1, sc1, hs1, 0);
    layer(xbh, xbl, cb1h, cb1l, 4, thpre2, thpost2, memk2, memv2, sc2, hs2, 1);
}

// Round 7
// 1647.015 us; speedup vs baseline: 1.3865x; 1.0518x over previous
//
#include <hip/hip_runtime.h>

#define DEVI __device__ __forceinline__

typedef unsigned short u16;
typedef __attribute__((ext_vector_type(8))) _Float16 f16x8;
typedef __attribute__((ext_vector_type(4))) float f32x4;

#define NQ   2048
#define DIMM 1024
#define HD   16
#define MM   16
#define JTOT 2064   // MM + NC
#define JPK  2080   // padded kn rows (65*32)
#define JPAD 2112   // padded j stride (66*32)
#define KTOP 64
#define EPITCH 2114 // E row pitch (f16): 1057 dwords, odd -> conflict-free

DEVI u16 f2h(float x) {
    _Float16 h = (_Float16)x;
    u16 r; __builtin_memcpy(&r, &h, 2); return r;
}
DEVI void fsplit(float x, u16& hi, u16& lo) {
    _Float16 h = (_Float16)x;
    float r = x - (float)h;
    _Float16 l = (_Float16)r;
    __builtin_memcpy(&hi, &h, 2);
    __builtin_memcpy(&lo, &l, 2);
}

// ---------------- split-cast a f32 tensor to (hi, lo) f16 pair --------------
__global__ __launch_bounds__(256) void split1_kernel(
    const float* __restrict__ s, u16* __restrict__ hi, u16* __restrict__ lo, int n4)
{
    int gid = blockIdx.x * 256 + threadIdx.x;
    if (gid < n4) {
        float4 v = ((const float4*)s)[gid];
        ushort4 h, l;
        fsplit(v.x, h.x, l.x); fsplit(v.y, h.y, l.y);
        fsplit(v.z, h.z, l.z); fsplit(v.w, h.w, l.w);
        ((ushort4*)hi)[gid] = h;
        ((ushort4*)lo)[gid] = l;
    }
}

// ---------------- transpose + split-cast the 8 weight matrices --------------
struct P8 { const float* w[8]; };

__global__ __launch_bounds__(256) void wtrans_kernel(P8 src, u16* WTh, u16* WTl) {
    __shared__ float T[64][65];
    const float* W = src.w[blockIdx.z];
    size_t off = (size_t)blockIdx.z * DIMM * DIMM;
    int n0 = blockIdx.x * 64, k0 = blockIdx.y * 64;
#pragma unroll
    for (int rep = 0; rep < 16; ++rep) {
        int idx = rep * 256 + threadIdx.x;
        int kk = idx >> 6, nn = idx & 63;
        T[kk][nn] = W[(size_t)(k0 + kk) * DIMM + n0 + nn];
    }
    __syncthreads();
#pragma unroll
    for (int rep = 0; rep < 16; ++rep) {
        int idx = rep * 256 + threadIdx.x;
        int nn = idx >> 6, kk = idx & 63;
        u16 h, l; fsplit(T[kk][nn], h, l);
        WTh[off + (size_t)(n0 + nn) * DIMM + k0 + kk] = h;
        WTl[off + (size_t)(n0 + nn) * DIMM + k0 + kk] = l;
    }
}

// ------- plain NT f16 MFMA GEMM  C[M,N] = A[M,K] * B[N,K]^T (batched) -------
// OM 0: f32 out, 1: f16 out.
template<int OM>
__global__ __launch_bounds__(256) void gemm_nt(
    const u16* __restrict__ A, int lda, long sA,
    const u16* __restrict__ B, int ldb, long sB,
    void* __restrict__ Cv, int ldc, long sC, int K)
{
    __shared__ u16 As[64 * 40];
    __shared__ u16 Bs[64 * 40];
    const int tid = threadIdx.x;
    const int z = blockIdx.z;
    A += (size_t)z * sA; B += (size_t)z * sB;
    const int bm = blockIdx.x * 64, bn = blockIdx.y * 64;
    const int l = tid & 63, w = tid >> 6;
    const int wm = (w >> 1) * 32, wn = (w & 1) * 32;
    const int srow = tid >> 2, skcol = (tid & 3) * 8;
    const u16* Ag = A + (size_t)(bm + srow) * lda + skcol;
    const u16* Bg = B + (size_t)(bn + srow) * ldb + skcol;
    const int lr = l & 15, lk = (l >> 4) * 8;
    f32x4 acc[2][2] = {};
    for (int k0 = 0; k0 < K; k0 += 32) {
        uint4 av = *(const uint4*)(Ag + k0);
        uint4 bv = *(const uint4*)(Bg + k0);
        __syncthreads();
        *(uint4*)&As[srow * 40 + skcol] = av;
        *(uint4*)&Bs[srow * 40 + skcol] = bv;
        __syncthreads();
        f16x8 a0 = *(const f16x8*)&As[(wm + lr) * 40 + lk];
        f16x8 a1 = *(const f16x8*)&As[(wm + 16 + lr) * 40 + lk];
        f16x8 b0 = *(const f16x8*)&Bs[(wn + lr) * 40 + lk];
        f16x8 b1 = *(const f16x8*)&Bs[(wn + 16 + lr) * 40 + lk];
        acc[0][0] = __builtin_amdgcn_mfma_f32_16x16x32_f16(a0, b0, acc[0][0], 0, 0, 0);
        acc[0][1] = __builtin_amdgcn_mfma_f32_16x16x32_f16(a0, b1, acc[0][1], 0, 0, 0);
        acc[1][0] = __builtin_amdgcn_mfma_f32_16x16x32_f16(a1, b0, acc[1][0], 0, 0, 0);
        acc[1][1] = __builtin_amdgcn_mfma_f32_16x16x32_f16(a1, b1, acc[1][1], 0, 0, 0);
    }
    const int crow0 = bm + wm + (l >> 4) * 4;
    const int ccol0 = bn + wn + lr;
#pragma unroll
    for (int mi = 0; mi < 2; ++mi)
#pragma unroll
        for (int ni = 0; ni < 2; ++ni)
#pragma unroll
            for (int r = 0; r < 4; ++r) {
                int row = crow0 + mi * 16 + r;
                int col = ccol0 + ni * 16;
                if (OM == 0) {
                    float* C = (float*)Cv + (size_t)z * sC;
                    C[(size_t)row * ldc + col] = acc[mi][ni][r];
                } else {
                    u16* C = (u16*)Cv + (size_t)z * sC;
                    C[(size_t)row * ldc + col] = f2h(acc[mi][ni][r]);
                }
            }
}

// ---- split-f16 3-term NT GEMM: C = (Ah+Al)(Bh+Bl)^T, f32 out (z=1) --------
__global__ __launch_bounds__(256) void gemm3_nt(
    const u16* __restrict__ Ah, const u16* __restrict__ Al, int lda,
    const u16* __restrict__ Bh, const u16* __restrict__ Bl, int ldb,
    float* __restrict__ C, int ldc, int K)
{
    __shared__ u16 Ash[64 * 40];
    __shared__ u16 Asl[64 * 40];
    __shared__ u16 Bsh[64 * 40];
    __shared__ u16 Bsl[64 * 40];
    const int tid = threadIdx.x;
    const int bm = blockIdx.x * 64, bn = blockIdx.y * 64;
    const int l = tid & 63, w = tid >> 6;
    const int wm = (w >> 1) * 32, wn = (w & 1) * 32;
    const int srow = tid >> 2, skcol = (tid & 3) * 8;
    const size_t aoff = (size_t)(bm + srow) * lda + skcol;
    const size_t boff = (size_t)(bn + srow) * ldb + skcol;
    const int lr = l & 15, lk = (l >> 4) * 8;
    f32x4 acc[2][2] = {};
    for (int k0 = 0; k0 < K; k0 += 32) {
        uint4 avh = *(const uint4*)(Ah + aoff + k0);
        uint4 avl = *(const uint4*)(Al + aoff + k0);
        uint4 bvh = *(const uint4*)(Bh + boff + k0);
        uint4 bvl = *(const uint4*)(Bl + boff + k0);
        __syncthreads();
        *(uint4*)&Ash[srow * 40 + skcol] = avh;
        *(uint4*)&Asl[srow * 40 + skcol] = avl;
        *(uint4*)&Bsh[srow * 40 + skcol] = bvh;
        *(uint4*)&Bsl[srow * 40 + skcol] = bvl;
        __syncthreads();
        f16x8 a0h = *(const f16x8*)&Ash[(wm + lr) * 40 + lk];
        f16x8 a1h = *(const f16x8*)&Ash[(wm + 16 + lr) * 40 + lk];
        f16x8 a0l = *(const f16x8*)&Asl[(wm + lr) * 40 + lk];
        f16x8 a1l = *(const f16x8*)&Asl[(wm + 16 + lr) * 40 + lk];
        f16x8 b0h = *(const f16x8*)&Bsh[(wn + lr) * 40 + lk];
        f16x8 b1h = *(const f16x8*)&Bsh[(wn + 16 + lr) * 40 + lk];
        f16x8 b0l = *(const f16x8*)&Bsl[(wn + lr) * 40 + lk];
        f16x8 b1l = *(const f16x8*)&Bsl[(wn + 16 + lr) * 40 + lk];
#define MF(acc_, a_, b_) acc_ = __builtin_amdgcn_mfma_f32_16x16x32_f16(a_, b_, acc_, 0, 0, 0)
        MF(acc[0][0], a0h, b0h); MF(acc[0][0], a0h, b0l); MF(acc[0][0], a0l, b0h);
        MF(acc[0][1], a0h, b1h); MF(acc[0][1], a0h, b1l); MF(acc[0][1], a0l, b1h);
        MF(acc[1][0], a1h, b0h); MF(acc[1][0], a1h, b0l); MF(acc[1][0], a1l, b0h);
        MF(acc[1][1], a1h, b1h); MF(acc[1][1], a1h, b1l); MF(acc[1][1], a1l, b1h);
#undef MF
    }
    const int crow0 = bm + wm + (l >> 4) * 4;
    const int ccol0 = bn + wn + lr;
#pragma unroll
    for (int mi = 0; mi < 2; ++mi)
#pragma unroll
        for (int ni = 0; ni < 2; ++ni)
#pragma unroll
            for (int r = 0; r < 4; ++r)
                C[(size_t)(crow0 + mi * 16 + r) * ldc + ccol0 + ni * 16] = acc[mi][ni][r];
}

// ------- normalize Q (fold per-head scale), write split f16 [h][i][64] ------
__global__ __launch_bounds__(256) void normq_kernel(
    const float* __restrict__ Qf, const float* __restrict__ scp,
    u16* __restrict__ qnh, u16* __restrict__ qnl)
{
    int w = threadIdx.x >> 6, l = threadIdx.x & 63;
    int wid = blockIdx.x * 4 + w;        // [0, 16*2048)
    int h = wid >> 11, i = wid & 2047;
    float x = Qf[(size_t)i * DIMM + h * 64 + l];
    float ss = x * x;
#pragma unroll
    for (int m = 32; m; m >>= 1) ss += __shfl_xor(ss, m);
    float inv = 1.0f / fmaxf(sqrtf(ss), 1e-12f);
    float sc = 1.0f / fmaxf(expf(scp[h]), 0.01f);
    u16 hh, ll; fsplit(x * inv * sc, hh, ll);
    size_t idx = ((size_t)h * NQ + i) * 64 + l;
    qnh[idx] = hh; qnl[idx] = ll;
}

// ------- build normalized K (mem-prepend + zero pad), split f16 -------------
__global__ __launch_bounds__(256) void buildkn_kernel(
    const float* __restrict__ Kf, const float* __restrict__ mem_k,
    u16* __restrict__ knh, u16* __restrict__ knl)
{
    int w = threadIdx.x >> 6, l = threadIdx.x & 63;
    int wid = blockIdx.x * 4 + w;        // [0, 16*2080)
    int h = wid / JPK, j = wid - h * JPK;
    float x = (j < MM) ? mem_k[((size_t)h * MM + j) * 64 + l]
            : (j < JTOT) ? Kf[(size_t)(j - MM) * DIMM + h * 64 + l] : 0.0f;
    float ss = x * x;
#pragma unroll
    for (int m = 32; m; m >>= 1) ss += __shfl_xor(ss, m);
    float inv = 1.0f / fmaxf(sqrtf(ss), 1e-12f);
    u16 hh, ll; fsplit(x * inv, hh, ll);
    size_t idx = ((size_t)h * JPK + j) * 64 + l;
    knh[idx] = hh; knl[idx] = ll;
}

// ---------------- build V^T (mem-prepend, head_scale folded), f16 ----------
__global__ __launch_bounds__(256) void buildvvT_kernel(
    const float* __restrict__ Vf, const float* __restrict__ mem_v,
    const float* __restrict__ hsp, u16* __restrict__ vvT)
{
    __shared__ float T[64][65];
    int h = blockIdx.z, j0 = blockIdx.x * 64;
    float hs = hsp[h];
#pragma unroll
    for (int rep = 0; rep < 16; ++rep) {
        int idx = rep * 256 + threadIdx.x;
        int jl = idx >> 6, d = idx & 63;
        int j = j0 + jl;
        float x = (j < MM) ? mem_v[((size_t)h * MM + j) * 64 + d]
                : (j < JTOT) ? Vf[(size_t)(j - MM) * DIMM + h * 64 + d] : 0.0f;
        T[jl][d] = x * hs;
    }
    __syncthreads();
#pragma unroll
    for (int rep = 0; rep < 16; ++rep) {
        int idx = rep * 256 + threadIdx.x;
        int d = idx >> 6, jl = idx & 63;
        vvT[((size_t)h * 64 + d) * JPAD + j0 + jl] = f2h(T[jl][d]);
    }
}

// ------- fused per-head QK^T (split-f16) + th_pre mix, h split over waves ---
// D layout: [i_local][h][j]  (h stride JPAD, i stride 16*JPAD)
__global__ __launch_bounds__(256) void dots_kernel(
    const u16* __restrict__ qnh, const u16* __restrict__ qnl,
    const u16* __restrict__ knh, const u16* __restrict__ knl,
    const float* __restrict__ th_pre, float* __restrict__ D,
    int q0, int NQC)
{
    __shared__ float red[4][8][256];   // 32 KB
    const int tid = threadIdx.x, l = tid & 63, w = tid >> 6;
    const int it = blockIdx.x * 16;
    const int jt = blockIdx.y * 16;
    const int lr = l & 15, lk = (l >> 4) * 8;
    const int qrow = q0 + it + lr;
    const int jrow = jt + lr;
    f32x4 accg[16] = {};
#pragma unroll
    for (int hh = 0; hh < 4; ++hh) {
        const int h = w * 4 + hh;
        size_t qo = (((size_t)h * NQ + qrow) << 6) + lk;
        size_t ko = (((size_t)h * JPK + jrow) << 6) + lk;
        const f16x8* pah = (const f16x8*)(qnh + qo);
        const f16x8* pal = (const f16x8*)(qnl + qo);
        const f16x8* pbh = (const f16x8*)(knh + ko);
        const f16x8* pbl = (const f16x8*)(knl + ko);
        f16x8 a0h = pah[0], a1h = pah[4];
        f16x8 a0l = pal[0], a1l = pal[4];
        f16x8 b0h = pbh[0], b1h = pbh[4];
        f16x8 b0l = pbl[0], b1l = pbl[4];
        f32x4 ah = {};
        ah = __builtin_amdgcn_mfma_f32_16x16x32_f16(a0h, b0h, ah, 0, 0, 0);
        ah = __builtin_amdgcn_mfma_f32_16x16x32_f16(a1h, b1h, ah, 0, 0, 0);
        ah = __builtin_amdgcn_mfma_f32_16x16x32_f16(a0h, b0l, ah, 0, 0, 0);
        ah = __builtin_amdgcn_mfma_f32_16x16x32_f16(a1h, b1l, ah, 0, 0, 0);
        ah = __builtin_amdgcn_mfma_f32_16x16x32_f16(a0l, b0h, ah, 0, 0, 0);
        ah = __builtin_amdgcn_mfma_f32_16x16x32_f16(a1l, b1h, ah, 0, 0, 0);
#pragma unroll
        for (int g = 0; g < 16; ++g)
            accg[g] += th_pre[g * 16 + h] * ah;
    }
    const int orow = it + (l >> 4) * 4;
    const int col = jt + lr;
#pragma unroll
    for (int ph = 0; ph < 2; ++ph) {
        __syncthreads();
#pragma unroll
        for (int g = 0; g < 8; ++g)
            *(f32x4*)&red[w][g][l * 4] = accg[ph * 8 + g];
        __syncthreads();
#pragma unroll
        for (int gq = 0; gq < 2; ++gq) {
            const int gl = w * 2 + gq;
            f32x4 s = *(const f32x4*)&red[0][gl][l * 4];
            s += *(const f32x4*)&red[1][gl][l * 4];
            s += *(const f32x4*)&red[2][gl][l * 4];
            s += *(const f32x4*)&red[3][gl][l * 4];
            const int g = ph * 8 + gl;
#pragma unroll
            for (int r = 0; r < 4; ++r)
                D[((size_t)(orow + r) * 16 + g) * JPAD + col] = s[r];
        }
    }
}

// ---- FUSED stats + softmax + MFMA th_post mix. One block per query row i.
// Phase A: wave w: exact ballot-radix top-k + stats for h=4w..4w+3; e values
// (register-resident) normalized and stored f16 to LDS E[h][j].
// Phase B: th_post mix via one mfma_f32_16x16x32_f16 per 16-j tile
// (A = th_post zero-padded K=32 — layout identical to validated smfused).
__global__ __launch_bounds__(256) void smix2_kernel(
    const float* __restrict__ D, const float* __restrict__ th_post,
    u16* __restrict__ P)
{
    __shared__ u16 E[16][EPITCH];      // 67.6 KB
    const int tid = threadIdx.x, l = tid & 63, w = tid >> 6;
    const int i = blockIdx.x;
    // -------- phase A --------
    for (int hh = 0; hh < 4; ++hh) {
        const int h = w * 4 + hh;
        const float* Dr = D + ((size_t)i * 16 + h) * JPAD;
        float v[33]; unsigned ku[33];
#pragma unroll
        for (int s = 0; s < 33; ++s) {
            int j = s * 64 + l;
            float x = (j < JTOT) ? Dr[j] : -3.0e38f;
            v[s] = x;
            unsigned u = __float_as_uint(x);
            ku[s] = (j < JTOT) ? ((u & 0x80000000u) ? ~u : (u | 0x80000000u)) : 0u;
        }
        unsigned t = 0;
        for (int b = 31; b >= 0; --b) {
            unsigned tc = t | (1u << b);
            int c = 0;
#pragma unroll
            for (int s = 0; s < 33; ++s)
                c += (int)__popcll(__ballot(ku[s] >= tc));
            if (c >= KTOP) t = tc;
        }
        float mx = v[0];
#pragma unroll
        for (int s = 1; s < 33; ++s) mx = fmaxf(mx, v[s]);
#pragma unroll
        for (int m = 32; m; m >>= 1) mx = fmaxf(mx, __shfl_xor(mx, m));
        float den = 0.0f;
#pragma unroll
        for (int s = 0; s < 33; ++s) {
            float ev = (ku[s] >= t) ? __expf(v[s] - mx) : 0.0f;
            v[s] = ev; den += ev;
        }
#pragma unroll
        for (int m = 32; m; m >>= 1) den += __shfl_xor(den, m);
        float inv = 1.0f / den;
#pragma unroll
        for (int s = 0; s < 33; ++s)
            E[h][s * 64 + l] = f2h(v[s] * inv);
    }
    __syncthreads();
    // -------- phase B: MFMA mix --------
    const int g = l & 15, hg = l >> 4, hb = (hg & 1) * 8;
    f16x8 afr;
#pragma unroll
    for (int idx = 0; idx < 8; ++idx) {
        int k = hg * 8 + idx;
        afr[idx] = (_Float16)((k < 16) ? th_post[g * 16 + k] : 0.0f);
    }
    for (int t = w; t < 129; t += 4) {
        const int j = t * 16 + g;
        f16x8 bfr;
#pragma unroll
        for (int idx = 0; idx < 8; ++idx) {
            u16 raw = E[hb + idx][j];
            _Float16 hv; __builtin_memcpy(&hv, &raw, 2);
            bfr[idx] = hv;
        }
        f32x4 c = {};
        c = __builtin_amdgcn_mfma_f32_16x16x32_f16(afr, bfr, c, 0, 0, 0);
#pragma unroll
        for (int r = 0; r < 4; ++r) {
            const int gg = hg * 4 + r;
            P[((size_t)i * 16 + gg) * JPAD + j] = f2h(c[r]);
        }
    }
}

// ============================================================================
extern "C" void kernel_launch(void* const* d_in, const int* in_sizes, int n_in,
                              void* d_out, int out_size, void* d_ws, size_t ws_size,
                              hipStream_t stream)
{
    (void)in_sizes; (void)n_in; (void)out_size;
    const float* x      = (const float*)d_in[0];
    const float* ctx    = (const float*)d_in[1];
    const float* Wq1    = (const float*)d_in[4];
    const float* Wk1    = (const float*)d_in[5];
    const float* Wv1    = (const float*)d_in[6];
    const float* Wq2    = (const float*)d_in[7];
    const float* Wk2    = (const float*)d_in[8];
    const float* Wv2    = (const float*)d_in[9];
    const float* thpre1 = (const float*)d_in[10];
    const float* thpost1= (const float*)d_in[11];
    const float* thpre2 = (const float*)d_in[12];
    const float* thpost2= (const float*)d_in[13];
    const float* memk1  = (const float*)d_in[14];
    const float* memv1  = (const float*)d_in[15];
    const float* memk2  = (const float*)d_in[16];
    const float* memv2  = (const float*)d_in[17];
    const float* sc1    = (const float*)d_in[18];
    const float* sc2    = (const float*)d_in[19];
    const float* hs1    = (const float*)d_in[20];
    const float* hs2    = (const float*)d_in[21];
    const float* Wo1    = (const float*)d_in[22];
    const float* Wo2    = (const float*)d_in[23];

    char* p = (char*)d_ws;
    auto alloc = [&](size_t n) { char* r = p; p += (n + 255) & ~(size_t)255; return r; };
    u16*   xbh   = (u16*)alloc((size_t)NQ * DIMM * 2);
    u16*   xbl   = (u16*)alloc((size_t)NQ * DIMM * 2);
    u16*   cb0h  = (u16*)alloc((size_t)NQ * DIMM * 2);
    u16*   cb0l  = (u16*)alloc((size_t)NQ * DIMM * 2);
    u16*   cb1h  = (u16*)alloc((size_t)NQ * DIMM * 2);
    u16*   cb1l  = (u16*)alloc((size_t)NQ * DIMM * 2);
    u16*   WTh   = (u16*)alloc((size_t)8 * DIMM * DIMM * 2);
    u16*   WTl   = (u16*)alloc((size_t)8 * DIMM * DIMM * 2);
    float* Qf    = (float*)alloc((size_t)NQ * DIMM * 4);   // also reused as x2f
    float* Kf    = (float*)alloc((size_t)NQ * DIMM * 4);
    float* Vf    = (float*)alloc((size_t)NQ * DIMM * 4);
    u16*   qnh   = (u16*)alloc((size_t)16 * NQ * 64 * 2);
    u16*   qnl   = (u16*)alloc((size_t)16 * NQ * 64 * 2);
    u16*   knh   = (u16*)alloc((size_t)16 * JPK * 64 * 2);
    u16*   knl   = (u16*)alloc((size_t)16 * JPK * 64 * 2);
    u16*   vvT   = (u16*)alloc((size_t)16 * 64 * JPAD * 2);
    u16*   attnA = (u16*)alloc((size_t)NQ * DIMM * 2);
    size_t used = (size_t)(p - (char*)d_ws);

    int NQC = 32;
    for (int cand : {512, 256, 128, 64}) {
        if (used + (size_t)16 * cand * JPAD * 6 + 1024 <= ws_size) { NQC = cand; break; }
    }
    float* Dbuf = (float*)alloc((size_t)16 * NQC * JPAD * 4);
    u16*   Pbuf = (u16*)alloc((size_t)16 * NQC * JPAD * 2);

    // ---- one-time split-casts ----
    const int N4 = (NQ * DIMM) / 4;
    split1_kernel<<<2048, 256, 0, stream>>>(x, xbh, xbl, N4);
    split1_kernel<<<2048, 256, 0, stream>>>(ctx, cb0h, cb0l, N4);
    split1_kernel<<<2048, 256, 0, stream>>>(ctx + (size_t)NQ * DIMM, cb1h, cb1l, N4);
    P8 w8{ { Wq1, Wk1, Wv1, Wo1, Wq2, Wk2, Wv2, Wo2 } };
    wtrans_kernel<<<dim3(16, 16, 8), 256, 0, stream>>>(w8, WTh, WTl);

    auto layer = [&](const u16* inh, const u16* inl,
                     const u16* ctxh, const u16* ctxl, int wbase,
                     const float* thpre, const float* thpost,
                     const float* memk, const float* memv,
                     const float* scp, const float* hsp, int li) {
        size_t o_q = (size_t)(wbase + 0) * DIMM * DIMM;
        size_t o_k = (size_t)(wbase + 1) * DIMM * DIMM;
        size_t o_v = (size_t)(wbase + 2) * DIMM * DIMM;
        size_t o_o = (size_t)(wbase + 3) * DIMM * DIMM;
        gemm3_nt<<<dim3(32, 16), 256, 0, stream>>>(inh, inl, DIMM, WTh + o_q, WTl + o_q, DIMM, Qf, DIMM, DIMM);
        gemm3_nt<<<dim3(32, 16), 256, 0, stream>>>(ctxh, ctxl, DIMM, WTh + o_k, WTl + o_k, DIMM, Kf, DIMM, DIMM);
        gemm_nt<0><<<dim3(32, 16, 1), 256, 0, stream>>>(ctxh, DIMM, 0, WTh + o_v, DIMM, 0, Vf, DIMM, 0, DIMM);
        normq_kernel<<<(16 * NQ) / 4, 256, 0, stream>>>(Qf, scp, qnh, qnl);
        buildkn_kernel<<<(16 * JPK) / 4, 256, 0, stream>>>(Kf, memk, knh, knl);
        buildvvT_kernel<<<dim3(33, 1, 16), 256, 0, stream>>>(Vf, memv, hsp, vvT);
        int nch = NQ / NQC;
        for (int c = 0; c < nch; ++c) {
            int q0 = c * NQC;
            dots_kernel<<<dim3(NQC / 16, JTOT / 16), 256, 0, stream>>>(qnh, qnl, knh, knl, thpre, Dbuf, q0, NQC);
            smix2_kernel<<<NQC, 256, 0, stream>>>(Dbuf, thpost, Pbuf);
            gemm_nt<1><<<dim3(NQC / 64, 1, 16), 256, 0, stream>>>(
                Pbuf, 16 * JPAD, (long)JPAD, vvT, JPAD, (long)64 * JPAD,
                attnA + (size_t)q0 * DIMM, DIMM, 64, JPAD);
        }
        if (li == 0) {
            // f32 layer-1 output into Qf (dead here), then split for layer 2
            gemm_nt<0><<<dim3(32, 16, 1), 256, 0, stream>>>(attnA, DIMM, 0, WTh + o_o, DIMM, 0, Qf, DIMM, 0, DIMM);
            split1_kernel<<<2048, 256, 0, stream>>>(Qf, xbh, xbl, N4);
        } else {
            gemm_nt<0><<<dim3(32, 16, 1), 256, 0, stream>>>(attnA, DIMM, 0, WTh + o_o, DIMM, 0, d_out, DIMM, 0, DIMM);
        }
    };

    layer(xbh, xbl, cb0h, cb0l, 0, thpre1, thpost1, memk1, memv1, sc1, hs1, 0);
    layer(xbh, xbl, cb1h, cb1l, 4, thpre2, thpost2, memk2, memv2, sc2, hs2, 1);
}

// Round 8
// 1573.955 us; speedup vs baseline: 1.4509x; 1.0464x over previous
//
#include <hip/hip_runtime.h>

#define DEVI __device__ __forceinline__

typedef unsigned short u16;
typedef __attribute__((ext_vector_type(8))) _Float16 f16x8;
typedef __attribute__((ext_vector_type(4))) float f32x4;

#define NQ   2048
#define DIMM 1024
#define HD   16
#define MM   16
#define JTOT 2064   // MM + NC
#define JPK  2080   // padded kn rows (65*32)
#define JPAD 2112   // padded j stride (66*32)
#define KTOP 64

DEVI u16 f2h(float x) {
    _Float16 h = (_Float16)x;
    u16 r; __builtin_memcpy(&r, &h, 2); return r;
}
DEVI void fsplit(float x, u16& hi, u16& lo) {
    _Float16 h = (_Float16)x;
    float r = x - (float)h;
    _Float16 l = (_Float16)r;
    __builtin_memcpy(&hi, &h, 2);
    __builtin_memcpy(&lo, &l, 2);
}

// ---------------- split-cast a f32 tensor to (hi, lo) f16 pair --------------
__global__ __launch_bounds__(256) void split1_kernel(
    const float* __restrict__ s, u16* __restrict__ hi, u16* __restrict__ lo, int n4)
{
    int gid = blockIdx.x * 256 + threadIdx.x;
    if (gid < n4) {
        float4 v = ((const float4*)s)[gid];
        ushort4 h, l;
        fsplit(v.x, h.x, l.x); fsplit(v.y, h.y, l.y);
        fsplit(v.z, h.z, l.z); fsplit(v.w, h.w, l.w);
        ((ushort4*)hi)[gid] = h;
        ((ushort4*)lo)[gid] = l;
    }
}

// ---------------- transpose + split-cast the 8 weight matrices --------------
struct P8 { const float* w[8]; };

__global__ __launch_bounds__(256) void wtrans_kernel(P8 src, u16* WTh, u16* WTl) {
    __shared__ float T[64][65];
    const float* W = src.w[blockIdx.z];
    size_t off = (size_t)blockIdx.z * DIMM * DIMM;
    int n0 = blockIdx.x * 64, k0 = blockIdx.y * 64;
#pragma unroll
    for (int rep = 0; rep < 16; ++rep) {
        int idx = rep * 256 + threadIdx.x;
        int kk = idx >> 6, nn = idx & 63;
        T[kk][nn] = W[(size_t)(k0 + kk) * DIMM + n0 + nn];
    }
    __syncthreads();
#pragma unroll
    for (int rep = 0; rep < 16; ++rep) {
        int idx = rep * 256 + threadIdx.x;
        int nn = idx >> 6, kk = idx & 63;
        u16 h, l; fsplit(T[kk][nn], h, l);
        WTh[off + (size_t)(n0 + nn) * DIMM + k0 + kk] = h;
        WTl[off + (size_t)(n0 + nn) * DIMM + k0 + kk] = l;
    }
}

// ------- plain NT f16 MFMA GEMM  C[M,N] = A[M,K] * B[N,K]^T (batched) -------
// OM 0: f32 out, 1: f16 out.
template<int OM>
__global__ __launch_bounds__(256) void gemm_nt(
    const u16* __restrict__ A, int lda, long sA,
    const u16* __restrict__ B, int ldb, long sB,
    void* __restrict__ Cv, int ldc, long sC, int K)
{
    __shared__ u16 As[64 * 40];
    __shared__ u16 Bs[64 * 40];
    const int tid = threadIdx.x;
    const int z = blockIdx.z;
    A += (size_t)z * sA; B += (size_t)z * sB;
    const int bm = blockIdx.x * 64, bn = blockIdx.y * 64;
    const int l = tid & 63, w = tid >> 6;
    const int wm = (w >> 1) * 32, wn = (w & 1) * 32;
    const int srow = tid >> 2, skcol = (tid & 3) * 8;
    const u16* Ag = A + (size_t)(bm + srow) * lda + skcol;
    const u16* Bg = B + (size_t)(bn + srow) * ldb + skcol;
    const int lr = l & 15, lk = (l >> 4) * 8;
    f32x4 acc[2][2] = {};
    for (int k0 = 0; k0 < K; k0 += 32) {
        uint4 av = *(const uint4*)(Ag + k0);
        uint4 bv = *(const uint4*)(Bg + k0);
        __syncthreads();
        *(uint4*)&As[srow * 40 + skcol] = av;
        *(uint4*)&Bs[srow * 40 + skcol] = bv;
        __syncthreads();
        f16x8 a0 = *(const f16x8*)&As[(wm + lr) * 40 + lk];
        f16x8 a1 = *(const f16x8*)&As[(wm + 16 + lr) * 40 + lk];
        f16x8 b0 = *(const f16x8*)&Bs[(wn + lr) * 40 + lk];
        f16x8 b1 = *(const f16x8*)&Bs[(wn + 16 + lr) * 40 + lk];
        acc[0][0] = __builtin_amdgcn_mfma_f32_16x16x32_f16(a0, b0, acc[0][0], 0, 0, 0);
        acc[0][1] = __builtin_amdgcn_mfma_f32_16x16x32_f16(a0, b1, acc[0][1], 0, 0, 0);
        acc[1][0] = __builtin_amdgcn_mfma_f32_16x16x32_f16(a1, b0, acc[1][0], 0, 0, 0);
        acc[1][1] = __builtin_amdgcn_mfma_f32_16x16x32_f16(a1, b1, acc[1][1], 0, 0, 0);
    }
    const int crow0 = bm + wm + (l >> 4) * 4;
    const int ccol0 = bn + wn + lr;
#pragma unroll
    for (int mi = 0; mi < 2; ++mi)
#pragma unroll
        for (int ni = 0; ni < 2; ++ni)
#pragma unroll
            for (int r = 0; r < 4; ++r) {
                int row = crow0 + mi * 16 + r;
                int col = ccol0 + ni * 16;
                if (OM == 0) {
                    float* C = (float*)Cv + (size_t)z * sC;
                    C[(size_t)row * ldc + col] = acc[mi][ni][r];
                } else {
                    u16* C = (u16*)Cv + (size_t)z * sC;
                    C[(size_t)row * ldc + col] = f2h(acc[mi][ni][r]);
                }
            }
}

// ---- split-f16 3-term NT GEMM: C = (Ah+Al)(Bh+Bl)^T, f32 out (z=1) --------
__global__ __launch_bounds__(256) void gemm3_nt(
    const u16* __restrict__ Ah, const u16* __restrict__ Al, int lda,
    const u16* __restrict__ Bh, const u16* __restrict__ Bl, int ldb,
    float* __restrict__ C, int ldc, int K)
{
    __shared__ u16 Ash[64 * 40];
    __shared__ u16 Asl[64 * 40];
    __shared__ u16 Bsh[64 * 40];
    __shared__ u16 Bsl[64 * 40];
    const int tid = threadIdx.x;
    const int bm = blockIdx.x * 64, bn = blockIdx.y * 64;
    const int l = tid & 63, w = tid >> 6;
    const int wm = (w >> 1) * 32, wn = (w & 1) * 32;
    const int srow = tid >> 2, skcol = (tid & 3) * 8;
    const size_t aoff = (size_t)(bm + srow) * lda + skcol;
    const size_t boff = (size_t)(bn + srow) * ldb + skcol;
    const int lr = l & 15, lk = (l >> 4) * 8;
    f32x4 acc[2][2] = {};
    for (int k0 = 0; k0 < K; k0 += 32) {
        uint4 avh = *(const uint4*)(Ah + aoff + k0);
        uint4 avl = *(const uint4*)(Al + aoff + k0);
        uint4 bvh = *(const uint4*)(Bh + boff + k0);
        uint4 bvl = *(const uint4*)(Bl + boff + k0);
        __syncthreads();
        *(uint4*)&Ash[srow * 40 + skcol] = avh;
        *(uint4*)&Asl[srow * 40 + skcol] = avl;
        *(uint4*)&Bsh[srow * 40 + skcol] = bvh;
        *(uint4*)&Bsl[srow * 40 + skcol] = bvl;
        __syncthreads();
        f16x8 a0h = *(const f16x8*)&Ash[(wm + lr) * 40 + lk];
        f16x8 a1h = *(const f16x8*)&Ash[(wm + 16 + lr) * 40 + lk];
        f16x8 a0l = *(const f16x8*)&Asl[(wm + lr) * 40 + lk];
        f16x8 a1l = *(const f16x8*)&Asl[(wm + 16 + lr) * 40 + lk];
        f16x8 b0h = *(const f16x8*)&Bsh[(wn + lr) * 40 + lk];
        f16x8 b1h = *(const f16x8*)&Bsh[(wn + 16 + lr) * 40 + lk];
        f16x8 b0l = *(const f16x8*)&Bsl[(wn + lr) * 40 + lk];
        f16x8 b1l = *(const f16x8*)&Bsl[(wn + 16 + lr) * 40 + lk];
#define MF(acc_, a_, b_) acc_ = __builtin_amdgcn_mfma_f32_16x16x32_f16(a_, b_, acc_, 0, 0, 0)
        MF(acc[0][0], a0h, b0h); MF(acc[0][0], a0h, b0l); MF(acc[0][0], a0l, b0h);
        MF(acc[0][1], a0h, b1h); MF(acc[0][1], a0h, b1l); MF(acc[0][1], a0l, b1h);
        MF(acc[1][0], a1h, b0h); MF(acc[1][0], a1h, b0l); MF(acc[1][0], a1l, b0h);
        MF(acc[1][1], a1h, b1h); MF(acc[1][1], a1h, b1l); MF(acc[1][1], a1l, b1h);
#undef MF
    }
    const int crow0 = bm + wm + (l >> 4) * 4;
    const int ccol0 = bn + wn + lr;
#pragma unroll
    for (int mi = 0; mi < 2; ++mi)
#pragma unroll
        for (int ni = 0; ni < 2; ++ni)
#pragma unroll
            for (int r = 0; r < 4; ++r)
                C[(size_t)(crow0 + mi * 16 + r) * ldc + ccol0 + ni * 16] = acc[mi][ni][r];
}

// ------- normalize Q (fold per-head scale), write split f16 [h][i][64] ------
__global__ __launch_bounds__(256) void normq_kernel(
    const float* __restrict__ Qf, const float* __restrict__ scp,
    u16* __restrict__ qnh, u16* __restrict__ qnl)
{
    int w = threadIdx.x >> 6, l = threadIdx.x & 63;
    int wid = blockIdx.x * 4 + w;        // [0, 16*2048)
    int h = wid >> 11, i = wid & 2047;
    float x = Qf[(size_t)i * DIMM + h * 64 + l];
    float ss = x * x;
#pragma unroll
    for (int m = 32; m; m >>= 1) ss += __shfl_xor(ss, m);
    float inv = 1.0f / fmaxf(sqrtf(ss), 1e-12f);
    float sc = 1.0f / fmaxf(expf(scp[h]), 0.01f);
    u16 hh, ll; fsplit(x * inv * sc, hh, ll);
    size_t idx = ((size_t)h * NQ + i) * 64 + l;
    qnh[idx] = hh; qnl[idx] = ll;
}

// ------- build normalized K (mem-prepend + zero pad), split f16 -------------
__global__ __launch_bounds__(256) void buildkn_kernel(
    const float* __restrict__ Kf, const float* __restrict__ mem_k,
    u16* __restrict__ knh, u16* __restrict__ knl)
{
    int w = threadIdx.x >> 6, l = threadIdx.x & 63;
    int wid = blockIdx.x * 4 + w;        // [0, 16*2080)
    int h = wid / JPK, j = wid - h * JPK;
    float x = (j < MM) ? mem_k[((size_t)h * MM + j) * 64 + l]
            : (j < JTOT) ? Kf[(size_t)(j - MM) * DIMM + h * 64 + l] : 0.0f;
    float ss = x * x;
#pragma unroll
    for (int m = 32; m; m >>= 1) ss += __shfl_xor(ss, m);
    float inv = 1.0f / fmaxf(sqrtf(ss), 1e-12f);
    u16 hh, ll; fsplit(x * inv, hh, ll);
    size_t idx = ((size_t)h * JPK + j) * 64 + l;
    knh[idx] = hh; knl[idx] = ll;
}

// ---------------- build V^T (mem-prepend, head_scale folded), f16 ----------
__global__ __launch_bounds__(256) void buildvvT_kernel(
    const float* __restrict__ Vf, const float* __restrict__ mem_v,
    const float* __restrict__ hsp, u16* __restrict__ vvT)
{
    __shared__ float T[64][65];
    int h = blockIdx.z, j0 = blockIdx.x * 64;
    float hs = hsp[h];
#pragma unroll
    for (int rep = 0; rep < 16; ++rep) {
        int idx = rep * 256 + threadIdx.x;
        int jl = idx >> 6, d = idx & 63;
        int j = j0 + jl;
        float x = (j < MM) ? mem_v[((size_t)h * MM + j) * 64 + d]
                : (j < JTOT) ? Vf[(size_t)(j - MM) * DIMM + h * 64 + d] : 0.0f;
        T[jl][d] = x * hs;
    }
    __syncthreads();
#pragma unroll
    for (int rep = 0; rep < 16; ++rep) {
        int idx = rep * 256 + threadIdx.x;
        int d = idx >> 6, jl = idx & 63;
        vvT[((size_t)h * 64 + d) * JPAD + j0 + jl] = f2h(T[jl][d]);
    }
}

// ------- fused per-head QK^T (split-f16) + th_pre mix, h split over waves ---
// D layout: [i_local][h][j]  (h stride JPAD, i stride 16*JPAD)
__global__ __launch_bounds__(256) void dots_kernel(
    const u16* __restrict__ qnh, const u16* __restrict__ qnl,
    const u16* __restrict__ knh, const u16* __restrict__ knl,
    const float* __restrict__ th_pre, float* __restrict__ D,
    int q0, int NQC)
{
    __shared__ float red[4][8][256];   // 32 KB
    const int tid = threadIdx.x, l = tid & 63, w = tid >> 6;
    const int it = blockIdx.x * 16;
    const int jt = blockIdx.y * 16;
    const int lr = l & 15, lk = (l >> 4) * 8;
    const int qrow = q0 + it + lr;
    const int jrow = jt + lr;
    f32x4 accg[16] = {};
#pragma unroll
    for (int hh = 0; hh < 4; ++hh) {
        const int h = w * 4 + hh;
        size_t qo = (((size_t)h * NQ + qrow) << 6) + lk;
        size_t ko = (((size_t)h * JPK + jrow) << 6) + lk;
        const f16x8* pah = (const f16x8*)(qnh + qo);
        const f16x8* pal = (const f16x8*)(qnl + qo);
        const f16x8* pbh = (const f16x8*)(knh + ko);
        const f16x8* pbl = (const f16x8*)(knl + ko);
        f16x8 a0h = pah[0], a1h = pah[4];
        f16x8 a0l = pal[0], a1l = pal[4];
        f16x8 b0h = pbh[0], b1h = pbh[4];
        f16x8 b0l = pbl[0], b1l = pbl[4];
        f32x4 ah = {};
        ah = __builtin_amdgcn_mfma_f32_16x16x32_f16(a0h, b0h, ah, 0, 0, 0);
        ah = __builtin_amdgcn_mfma_f32_16x16x32_f16(a1h, b1h, ah, 0, 0, 0);
        ah = __builtin_amdgcn_mfma_f32_16x16x32_f16(a0h, b0l, ah, 0, 0, 0);
        ah = __builtin_amdgcn_mfma_f32_16x16x32_f16(a1h, b1l, ah, 0, 0, 0);
        ah = __builtin_amdgcn_mfma_f32_16x16x32_f16(a0l, b0h, ah, 0, 0, 0);
        ah = __builtin_amdgcn_mfma_f32_16x16x32_f16(a1l, b1h, ah, 0, 0, 0);
#pragma unroll
        for (int g = 0; g < 16; ++g)
            accg[g] += th_pre[g * 16 + h] * ah;
    }
    const int orow = it + (l >> 4) * 4;
    const int col = jt + lr;
#pragma unroll
    for (int ph = 0; ph < 2; ++ph) {
        __syncthreads();
#pragma unroll
        for (int g = 0; g < 8; ++g)
            *(f32x4*)&red[w][g][l * 4] = accg[ph * 8 + g];
        __syncthreads();
#pragma unroll
        for (int gq = 0; gq < 2; ++gq) {
            const int gl = w * 2 + gq;
            f32x4 s = *(const f32x4*)&red[0][gl][l * 4];
            s += *(const f32x4*)&red[1][gl][l * 4];
            s += *(const f32x4*)&red[2][gl][l * 4];
            s += *(const f32x4*)&red[3][gl][l * 4];
            const int g = ph * 8 + gl;
#pragma unroll
            for (int r = 0; r < 4; ++r)
                D[((size_t)(orow + r) * 16 + g) * JPAD + col] = s[r];
        }
    }
}

// ---- exact top-k (ballot radix) + softmax; writes NORMALIZED f16 E ---------
// One row (i,h) per wave, 4 rows/block, grid 16*NQC/4 = high occupancy.
// E layout [i][h][j] (row r = i*16+h, stride JPAD); pad columns get 0.
__global__ __launch_bounds__(256) void estats_kernel(
    const float* __restrict__ D, u16* __restrict__ E)
{
    const int w = threadIdx.x >> 6, l = threadIdx.x & 63;
    const int r = blockIdx.x * 4 + w;
    const float* Dr = D + (size_t)r * JPAD;
    float v[33]; unsigned ku[33];
#pragma unroll
    for (int s = 0; s < 33; ++s) {
        int j = s * 64 + l;
        float x = (j < JTOT) ? Dr[j] : -3.0e38f;
        v[s] = x;
        unsigned u = __float_as_uint(x);
        ku[s] = (j < JTOT) ? ((u & 0x80000000u) ? ~u : (u | 0x80000000u)) : 0u;
    }
    unsigned t = 0;
    for (int b = 31; b >= 0; --b) {
        unsigned tc = t | (1u << b);
        int c = 0;
#pragma unroll
        for (int s = 0; s < 33; ++s)
            c += (int)__popcll(__ballot(ku[s] >= tc));
        if (c >= KTOP) t = tc;
    }
    float mx = v[0];
#pragma unroll
    for (int s = 1; s < 33; ++s) mx = fmaxf(mx, v[s]);
#pragma unroll
    for (int m = 32; m; m >>= 1) mx = fmaxf(mx, __shfl_xor(mx, m));
    float den = 0.0f;
#pragma unroll
    for (int s = 0; s < 33; ++s) {
        float ev = (ku[s] >= t) ? __expf(v[s] - mx) : 0.0f;
        v[s] = ev; den += ev;
    }
#pragma unroll
    for (int m = 32; m; m >>= 1) den += __shfl_xor(den, m);
    float inv = 1.0f / den;
    u16* Er = E + (size_t)r * JPAD;
#pragma unroll
    for (int s = 0; s < 33; ++s)
        Er[s * 64 + l] = f2h(v[s] * inv);
}

// ---- th_post head-mix via MFMA: P[i][g][j] = sum_h th_post[g,h] E[i][h][j].
// A-frag = th_post zero-padded to K=32 (validated layout). Grid NQC x 4.
__global__ __launch_bounds__(256) void mixp_kernel(
    const u16* __restrict__ E, const float* __restrict__ th_post,
    u16* __restrict__ P)
{
    const int tid = threadIdx.x, l = tid & 63, w = tid >> 6;
    const int i = blockIdx.x, by = blockIdx.y;
    const int g = l & 15, hg = l >> 4, hb = (hg & 1) * 8;
    f16x8 afr;
#pragma unroll
    for (int idx = 0; idx < 8; ++idx) {
        int k = hg * 8 + idx;
        afr[idx] = (_Float16)((k < 16) ? th_post[g * 16 + k] : 0.0f);
    }
    const u16* Eb = E + (size_t)i * 16 * JPAD;
    u16* Pb = P + (size_t)i * 16 * JPAD;
    for (int t = by * 4 + w; t < 129; t += 16) {
        const int j = t * 16 + g;
        f16x8 bfr;
#pragma unroll
        for (int idx = 0; idx < 8; ++idx) {
            u16 raw = Eb[(size_t)(hb + idx) * JPAD + j];
            _Float16 hv; __builtin_memcpy(&hv, &raw, 2);
            bfr[idx] = hv;
        }
        f32x4 c = {};
        c = __builtin_amdgcn_mfma_f32_16x16x32_f16(afr, bfr, c, 0, 0, 0);
#pragma unroll
        for (int r = 0; r < 4; ++r)
            Pb[(size_t)(hg * 4 + r) * JPAD + j] = f2h(c[r]);
    }
}

// ============================================================================
extern "C" void kernel_launch(void* const* d_in, const int* in_sizes, int n_in,
                              void* d_out, int out_size, void* d_ws, size_t ws_size,
                              hipStream_t stream)
{
    (void)in_sizes; (void)n_in; (void)out_size;
    const float* x      = (const float*)d_in[0];
    const float* ctx    = (const float*)d_in[1];
    const float* Wq1    = (const float*)d_in[4];
    const float* Wk1    = (const float*)d_in[5];
    const float* Wv1    = (const float*)d_in[6];
    const float* Wq2    = (const float*)d_in[7];
    const float* Wk2    = (const float*)d_in[8];
    const float* Wv2    = (const float*)d_in[9];
    const float* thpre1 = (const float*)d_in[10];
    const float* thpost1= (const float*)d_in[11];
    const float* thpre2 = (const float*)d_in[12];
    const float* thpost2= (const float*)d_in[13];
    const float* memk1  = (const float*)d_in[14];
    const float* memv1  = (const float*)d_in[15];
    const float* memk2  = (const float*)d_in[16];
    const float* memv2  = (const float*)d_in[17];
    const float* sc1    = (const float*)d_in[18];
    const float* sc2    = (const float*)d_in[19];
    const float* hs1    = (const float*)d_in[20];
    const float* hs2    = (const float*)d_in[21];
    const float* Wo1    = (const float*)d_in[22];
    const float* Wo2    = (const float*)d_in[23];

    char* p = (char*)d_ws;
    auto alloc = [&](size_t n) { char* r = p; p += (n + 255) & ~(size_t)255; return r; };
    u16*   xbh   = (u16*)alloc((size_t)NQ * DIMM * 2);
    u16*   xbl   = (u16*)alloc((size_t)NQ * DIMM * 2);
    u16*   cb0h  = (u16*)alloc((size_t)NQ * DIMM * 2);
    u16*   cb0l  = (u16*)alloc((size_t)NQ * DIMM * 2);
    u16*   cb1h  = (u16*)alloc((size_t)NQ * DIMM * 2);
    u16*   cb1l  = (u16*)alloc((size_t)NQ * DIMM * 2);
    u16*   WTh   = (u16*)alloc((size_t)8 * DIMM * DIMM * 2);
    u16*   WTl   = (u16*)alloc((size_t)8 * DIMM * DIMM * 2);
    float* Qf    = (float*)alloc((size_t)NQ * DIMM * 4);   // also reused as x2f
    float* Kf    = (float*)alloc((size_t)NQ * DIMM * 4);
    float* Vf    = (float*)alloc((size_t)NQ * DIMM * 4);
    u16*   qnh   = (u16*)alloc((size_t)16 * NQ * 64 * 2);
    u16*   qnl   = (u16*)alloc((size_t)16 * NQ * 64 * 2);
    u16*   knh   = (u16*)alloc((size_t)16 * JPK * 64 * 2);
    u16*   knl   = (u16*)alloc((size_t)16 * JPK * 64 * 2);
    u16*   vvT   = (u16*)alloc((size_t)16 * 64 * JPAD * 2);
    u16*   attnA = (u16*)alloc((size_t)NQ * DIMM * 2);
    size_t used = (size_t)(p - (char*)d_ws);

    int NQC = 32;
    for (int cand : {512, 256, 128, 64}) {
        if (used + (size_t)16 * cand * JPAD * 8 + 1024 <= ws_size) { NQC = cand; break; }
    }
    float* Dbuf = (float*)alloc((size_t)16 * NQC * JPAD * 4);
    u16*   Ebuf = (u16*)alloc((size_t)16 * NQC * JPAD * 2);
    u16*   Pbuf = (u16*)alloc((size_t)16 * NQC * JPAD * 2);

    // ---- one-time split-casts ----
    const int N4 = (NQ * DIMM) / 4;
    split1_kernel<<<2048, 256, 0, stream>>>(x, xbh, xbl, N4);
    split1_kernel<<<2048, 256, 0, stream>>>(ctx, cb0h, cb0l, N4);
    split1_kernel<<<2048, 256, 0, stream>>>(ctx + (size_t)NQ * DIMM, cb1h, cb1l, N4);
    P8 w8{ { Wq1, Wk1, Wv1, Wo1, Wq2, Wk2, Wv2, Wo2 } };
    wtrans_kernel<<<dim3(16, 16, 8), 256, 0, stream>>>(w8, WTh, WTl);

    auto layer = [&](const u16* inh, const u16* inl,
                     const u16* ctxh, const u16* ctxl, int wbase,
                     const float* thpre, const float* thpost,
                     const float* memk, const float* memv,
                     const float* scp, const float* hsp, int li) {
        size_t o_q = (size_t)(wbase + 0) * DIMM * DIMM;
        size_t o_k = (size_t)(wbase + 1) * DIMM * DIMM;
        size_t o_v = (size_t)(wbase + 2) * DIMM * DIMM;
        size_t o_o = (size_t)(wbase + 3) * DIMM * DIMM;
        gemm3_nt<<<dim3(32, 16), 256, 0, stream>>>(inh, inl, DIMM, WTh + o_q, WTl + o_q, DIMM, Qf, DIMM, DIMM);
        gemm3_nt<<<dim3(32, 16), 256, 0, stream>>>(ctxh, ctxl, DIMM, WTh + o_k, WTl + o_k, DIMM, Kf, DIMM, DIMM);
        gemm_nt<0><<<dim3(32, 16, 1), 256, 0, stream>>>(ctxh, DIMM, 0, WTh + o_v, DIMM, 0, Vf, DIMM, 0, DIMM);
        normq_kernel<<<(16 * NQ) / 4, 256, 0, stream>>>(Qf, scp, qnh, qnl);
        buildkn_kernel<<<(16 * JPK) / 4, 256, 0, stream>>>(Kf, memk, knh, knl);
        buildvvT_kernel<<<dim3(33, 1, 16), 256, 0, stream>>>(Vf, memv, hsp, vvT);
        int nch = NQ / NQC;
        for (int c = 0; c < nch; ++c) {
            int q0 = c * NQC;
            dots_kernel<<<dim3(NQC / 16, JTOT / 16), 256, 0, stream>>>(qnh, qnl, knh, knl, thpre, Dbuf, q0, NQC);
            estats_kernel<<<(16 * NQC) / 4, 256, 0, stream>>>(Dbuf, Ebuf);
            mixp_kernel<<<dim3(NQC, 4), 256, 0, stream>>>(Ebuf, thpost, Pbuf);
            gemm_nt<1><<<dim3(NQC / 64, 1, 16), 256, 0, stream>>>(
                Pbuf, 16 * JPAD, (long)JPAD, vvT, JPAD, (long)64 * JPAD,
                attnA + (size_t)q0 * DIMM, DIMM, 64, JPAD);
        }
        if (li == 0) {
            // f32 layer-1 output into Qf (dead here), then split for layer 2
            gemm_nt<0><<<dim3(32, 16, 1), 256, 0, stream>>>(attnA, DIMM, 0, WTh + o_o, DIMM, 0, Qf, DIMM, 0, DIMM);
            split1_kernel<<<2048, 256, 0, stream>>>(Qf, xbh, xbl, N4);
        } else {
            gemm_nt<0><<<dim3(32, 16, 1), 256, 0, stream>>>(attnA, DIMM, 0, WTh + o_o, DIMM, 0, d_out, DIMM, 0, DIMM);
        }
    };

    layer(xbh, xbl, cb0h, cb0l, 0, thpre1, thpost1, memk1, memv1, sc1, hs1, 0);
    layer(xbh, xbl, cb1h, cb1l, 4, thpre2, thpost2, memk2, memv2, sc2, hs2, 1);
}

// Round 10
// 1572.744 us; speedup vs baseline: 1.4520x; 1.0008x over previous
//
#include <hip/hip_runtime.h>

#define DEVI __device__ __forceinline__

typedef unsigned short u16;
typedef __attribute__((ext_vector_type(8))) _Float16 f16x8;
typedef __attribute__((ext_vector_type(4))) float f32x4;

#define NQ   2048
#define DIMM 1024
#define HD   16
#define MM   16
#define JTOT 2064   // MM + NC
#define JPK  2080   // padded kn rows (65*32)
#define JPAD 2112   // padded j stride (66*32)
#define KTOP 64

DEVI u16 f2h(float x) {
    _Float16 h = (_Float16)x;
    u16 r; __builtin_memcpy(&r, &h, 2); return r;
}
DEVI void fsplit(float x, u16& hi, u16& lo) {
    _Float16 h = (_Float16)x;
    float r = x - (float)h;
    _Float16 l = (_Float16)r;
    __builtin_memcpy(&hi, &h, 2);
    __builtin_memcpy(&lo, &l, 2);
}

// ---------------- split-cast a f32 tensor to (hi, lo) f16 pair --------------
__global__ __launch_bounds__(256) void split1_kernel(
    const float* __restrict__ s, u16* __restrict__ hi, u16* __restrict__ lo, int n4)
{
    int gid = blockIdx.x * 256 + threadIdx.x;
    if (gid < n4) {
        float4 v = ((const float4*)s)[gid];
        ushort4 h, l;
        fsplit(v.x, h.x, l.x); fsplit(v.y, h.y, l.y);
        fsplit(v.z, h.z, l.z); fsplit(v.w, h.w, l.w);
        ((ushort4*)hi)[gid] = h;
        ((ushort4*)lo)[gid] = l;
    }
}

// ---------------- transpose + split-cast the 8 weight matrices --------------
struct P8 { const float* w[8]; };

__global__ __launch_bounds__(256) void wtrans_kernel(P8 src, u16* WTh, u16* WTl) {
    __shared__ float T[64][65];
    const float* W = src.w[blockIdx.z];
    size_t off = (size_t)blockIdx.z * DIMM * DIMM;
    int n0 = blockIdx.x * 64, k0 = blockIdx.y * 64;
#pragma unroll
    for (int rep = 0; rep < 16; ++rep) {
        int idx = rep * 256 + threadIdx.x;
        int kk = idx >> 6, nn = idx & 63;
        T[kk][nn] = W[(size_t)(k0 + kk) * DIMM + n0 + nn];
    }
    __syncthreads();
#pragma unroll
    for (int rep = 0; rep < 16; ++rep) {
        int idx = rep * 256 + threadIdx.x;
        int nn = idx >> 6, kk = idx & 63;
        u16 h, l; fsplit(T[kk][nn], h, l);
        WTh[off + (size_t)(n0 + nn) * DIMM + k0 + kk] = h;
        WTl[off + (size_t)(n0 + nn) * DIMM + k0 + kk] = l;
    }
}

// ------- plain NT f16 MFMA GEMM  C[M,N] = A[M,K] * B[N,K]^T (batched) -------
// OM 0: f32 out, 1: f16 out.
template<int OM>
__global__ __launch_bounds__(256) void gemm_nt(
    const u16* __restrict__ A, int lda, long sA,
    const u16* __restrict__ B, int ldb, long sB,
    void* __restrict__ Cv, int ldc, long sC, int K)
{
    __shared__ u16 As[64 * 40];
    __shared__ u16 Bs[64 * 40];
    const int tid = threadIdx.x;
    const int z = blockIdx.z;
    A += (size_t)z * sA; B += (size_t)z * sB;
    const int bm = blockIdx.x * 64, bn = blockIdx.y * 64;
    const int l = tid & 63, w = tid >> 6;
    const int wm = (w >> 1) * 32, wn = (w & 1) * 32;
    const int srow = tid >> 2, skcol = (tid & 3) * 8;
    const u16* Ag = A + (size_t)(bm + srow) * lda + skcol;
    const u16* Bg = B + (size_t)(bn + srow) * ldb + skcol;
    const int lr = l & 15, lk = (l >> 4) * 8;
    f32x4 acc[2][2] = {};
    for (int k0 = 0; k0 < K; k0 += 32) {
        uint4 av = *(const uint4*)(Ag + k0);
        uint4 bv = *(const uint4*)(Bg + k0);
        __syncthreads();
        *(uint4*)&As[srow * 40 + skcol] = av;
        *(uint4*)&Bs[srow * 40 + skcol] = bv;
        __syncthreads();
        f16x8 a0 = *(const f16x8*)&As[(wm + lr) * 40 + lk];
        f16x8 a1 = *(const f16x8*)&As[(wm + 16 + lr) * 40 + lk];
        f16x8 b0 = *(const f16x8*)&Bs[(wn + lr) * 40 + lk];
        f16x8 b1 = *(const f16x8*)&Bs[(wn + 16 + lr) * 40 + lk];
        acc[0][0] = __builtin_amdgcn_mfma_f32_16x16x32_f16(a0, b0, acc[0][0], 0, 0, 0);
        acc[0][1] = __builtin_amdgcn_mfma_f32_16x16x32_f16(a0, b1, acc[0][1], 0, 0, 0);
        acc[1][0] = __builtin_amdgcn_mfma_f32_16x16x32_f16(a1, b0, acc[1][0], 0, 0, 0);
        acc[1][1] = __builtin_amdgcn_mfma_f32_16x16x32_f16(a1, b1, acc[1][1], 0, 0, 0);
    }
    const int crow0 = bm + wm + (l >> 4) * 4;
    const int ccol0 = bn + wn + lr;
#pragma unroll
    for (int mi = 0; mi < 2; ++mi)
#pragma unroll
        for (int ni = 0; ni < 2; ++ni)
#pragma unroll
            for (int r = 0; r < 4; ++r) {
                int row = crow0 + mi * 16 + r;
                int col = ccol0 + ni * 16;
                if (OM == 0) {
                    float* C = (float*)Cv + (size_t)z * sC;
                    C[(size_t)row * ldc + col] = acc[mi][ni][r];
                } else {
                    u16* C = (u16*)Cv + (size_t)z * sC;
                    C[(size_t)row * ldc + col] = f2h(acc[mi][ni][r]);
                }
            }
}

// ---- split-f16 3-term NT GEMM: C = (Ah+Al)(Bh+Bl)^T, f32 out (z=1) --------
__global__ __launch_bounds__(256) void gemm3_nt(
    const u16* __restrict__ Ah, const u16* __restrict__ Al, int lda,
    const u16* __restrict__ Bh, const u16* __restrict__ Bl, int ldb,
    float* __restrict__ C, int ldc, int K)
{
    __shared__ u16 Ash[64 * 40];
    __shared__ u16 Asl[64 * 40];
    __shared__ u16 Bsh[64 * 40];
    __shared__ u16 Bsl[64 * 40];
    const int tid = threadIdx.x;
    const int bm = blockIdx.x * 64, bn = blockIdx.y * 64;
    const int l = tid & 63, w = tid >> 6;
    const int wm = (w >> 1) * 32, wn = (w & 1) * 32;
    const int srow = tid >> 2, skcol = (tid & 3) * 8;
    const size_t aoff = (size_t)(bm + srow) * lda + skcol;
    const size_t boff = (size_t)(bn + srow) * ldb + skcol;
    const int lr = l & 15, lk = (l >> 4) * 8;
    f32x4 acc[2][2] = {};
    for (int k0 = 0; k0 < K; k0 += 32) {
        uint4 avh = *(const uint4*)(Ah + aoff + k0);
        uint4 avl = *(const uint4*)(Al + aoff + k0);
        uint4 bvh = *(const uint4*)(Bh + boff + k0);
        uint4 bvl = *(const uint4*)(Bl + boff + k0);
        __syncthreads();
        *(uint4*)&Ash[srow * 40 + skcol] = avh;
        *(uint4*)&Asl[srow * 40 + skcol] = avl;
        *(uint4*)&Bsh[srow * 40 + skcol] = bvh;
        *(uint4*)&Bsl[srow * 40 + skcol] = bvl;
        __syncthreads();
        f16x8 a0h = *(const f16x8*)&Ash[(wm + lr) * 40 + lk];
        f16x8 a1h = *(const f16x8*)&Ash[(wm + 16 + lr) * 40 + lk];
        f16x8 a0l = *(const f16x8*)&Asl[(wm + lr) * 40 + lk];
        f16x8 a1l = *(const f16x8*)&Asl[(wm + 16 + lr) * 40 + lk];
        f16x8 b0h = *(const f16x8*)&Bsh[(wn + lr) * 40 + lk];
        f16x8 b1h = *(const f16x8*)&Bsh[(wn + 16 + lr) * 40 + lk];
        f16x8 b0l = *(const f16x8*)&Bsl[(wn + lr) * 40 + lk];
        f16x8 b1l = *(const f16x8*)&Bsl[(wn + 16 + lr) * 40 + lk];
#define MF(acc_, a_, b_) acc_ = __builtin_amdgcn_mfma_f32_16x16x32_f16(a_, b_, acc_, 0, 0, 0)
        MF(acc[0][0], a0h, b0h); MF(acc[0][0], a0h, b0l); MF(acc[0][0], a0l, b0h);
        MF(acc[0][1], a0h, b1h); MF(acc[0][1], a0h, b1l); MF(acc[0][1], a0l, b1h);
        MF(acc[1][0], a1h, b0h); MF(acc[1][0], a1h, b0l); MF(acc[1][0], a1l, b0h);
        MF(acc[1][1], a1h, b1h); MF(acc[1][1], a1h, b1l); MF(acc[1][1], a1l, b1h);
#undef MF
    }
    const int crow0 = bm + wm + (l >> 4) * 4;
    const int ccol0 = bn + wn + lr;
#pragma unroll
    for (int mi = 0; mi < 2; ++mi)
#pragma unroll
        for (int ni = 0; ni < 2; ++ni)
#pragma unroll
            for (int r = 0; r < 4; ++r)
                C[(size_t)(crow0 + mi * 16 + r) * ldc + ccol0 + ni * 16] = acc[mi][ni][r];
}

// ------- normalize Q (fold per-head scale), write split f16 [h][i][64] ------
__global__ __launch_bounds__(256) void normq_kernel(
    const float* __restrict__ Qf, const float* __restrict__ scp,
    u16* __restrict__ qnh, u16* __restrict__ qnl)
{
    int w = threadIdx.x >> 6, l = threadIdx.x & 63;
    int wid = blockIdx.x * 4 + w;        // [0, 16*2048)
    int h = wid >> 11, i = wid & 2047;
    float x = Qf[(size_t)i * DIMM + h * 64 + l];
    float ss = x * x;
#pragma unroll
    for (int m = 32; m; m >>= 1) ss += __shfl_xor(ss, m);
    float inv = 1.0f / fmaxf(sqrtf(ss), 1e-12f);
    float sc = 1.0f / fmaxf(expf(scp[h]), 0.01f);
    u16 hh, ll; fsplit(x * inv * sc, hh, ll);
    size_t idx = ((size_t)h * NQ + i) * 64 + l;
    qnh[idx] = hh; qnl[idx] = ll;
}

// ------- build normalized K (mem-prepend + zero pad), split f16 -------------
__global__ __launch_bounds__(256) void buildkn_kernel(
    const float* __restrict__ Kf, const float* __restrict__ mem_k,
    u16* __restrict__ knh, u16* __restrict__ knl)
{
    int w = threadIdx.x >> 6, l = threadIdx.x & 63;
    int wid = blockIdx.x * 4 + w;        // [0, 16*2080)
    int h = wid / JPK, j = wid - h * JPK;
    float x = (j < MM) ? mem_k[((size_t)h * MM + j) * 64 + l]
            : (j < JTOT) ? Kf[(size_t)(j - MM) * DIMM + h * 64 + l] : 0.0f;
    float ss = x * x;
#pragma unroll
    for (int m = 32; m; m >>= 1) ss += __shfl_xor(ss, m);
    float inv = 1.0f / fmaxf(sqrtf(ss), 1e-12f);
    u16 hh, ll; fsplit(x * inv, hh, ll);
    size_t idx = ((size_t)h * JPK + j) * 64 + l;
    knh[idx] = hh; knl[idx] = ll;
}

// ---------------- build V^T (mem-prepend, head_scale folded), f16 ----------
__global__ __launch_bounds__(256) void buildvvT_kernel(
    const float* __restrict__ Vf, const float* __restrict__ mem_v,
    const float* __restrict__ hsp, u16* __restrict__ vvT)
{
    __shared__ float T[64][65];
    int h = blockIdx.z, j0 = blockIdx.x * 64;
    float hs = hsp[h];
#pragma unroll
    for (int rep = 0; rep < 16; ++rep) {
        int idx = rep * 256 + threadIdx.x;
        int jl = idx >> 6, d = idx & 63;
        int j = j0 + jl;
        float x = (j < MM) ? mem_v[((size_t)h * MM + j) * 64 + d]
                : (j < JTOT) ? Vf[(size_t)(j - MM) * DIMM + h * 64 + d] : 0.0f;
        T[jl][d] = x * hs;
    }
    __syncthreads();
#pragma unroll
    for (int rep = 0; rep < 16; ++rep) {
        int idx = rep * 256 + threadIdx.x;
        int d = idx >> 6, jl = idx & 63;
        vvT[((size_t)h * 64 + d) * JPAD + j0 + jl] = f2h(T[jl][d]);
    }
}

// ------- fused per-head QK^T (split-f16) + th_pre mix, h split over waves ---
// D layout: [i_local][h][j]  (h stride JPAD, i stride 16*JPAD)
// Reduction: EXACT round-8 form (2 phases x 8 g, red = 32 KB) — known good.
// Block index: XCD-aware bijective swizzle (m204 form; handles nwg%8 != 0).
__global__ __launch_bounds__(256) void dots_kernel(
    const u16* __restrict__ qnh, const u16* __restrict__ qnl,
    const u16* __restrict__ knh, const u16* __restrict__ knl,
    const float* __restrict__ th_pre, float* __restrict__ D,
    int q0, int NQC)
{
    __shared__ float red[4][8][256];   // 32 KB
    const int tid = threadIdx.x, l = tid & 63, w = tid >> 6;
    // --- bijective XCD swizzle of the linearized block id ---
    const int gx = gridDim.x, nwg = gx * gridDim.y;
    const int lin = blockIdx.y * gx + blockIdx.x;
    const int q8 = nwg >> 3, r8 = nwg & 7;
    const int xcd = lin & 7, idx8 = lin >> 3;
    const int swz = ((xcd < r8) ? xcd * (q8 + 1)
                                : r8 * (q8 + 1) + (xcd - r8) * q8) + idx8;
    const int it = (swz % gx) * 16;
    const int jt = (swz / gx) * 16;
    const int lr = l & 15, lk = (l >> 4) * 8;
    const int qrow = q0 + it + lr;
    const int jrow = jt + lr;
    f32x4 accg[16] = {};
#pragma unroll
    for (int hh = 0; hh < 4; ++hh) {
        const int h = w * 4 + hh;
        size_t qo = (((size_t)h * NQ + qrow) << 6) + lk;
        size_t ko = (((size_t)h * JPK + jrow) << 6) + lk;
        const f16x8* pah = (const f16x8*)(qnh + qo);
        const f16x8* pal = (const f16x8*)(qnl + qo);
        const f16x8* pbh = (const f16x8*)(knh + ko);
        const f16x8* pbl = (const f16x8*)(knl + ko);
        f16x8 a0h = pah[0], a1h = pah[4];
        f16x8 a0l = pal[0], a1l = pal[4];
        f16x8 b0h = pbh[0], b1h = pbh[4];
        f16x8 b0l = pbl[0], b1l = pbl[4];
        f32x4 ah = {};
        ah = __builtin_amdgcn_mfma_f32_16x16x32_f16(a0h, b0h, ah, 0, 0, 0);
        ah = __builtin_amdgcn_mfma_f32_16x16x32_f16(a1h, b1h, ah, 0, 0, 0);
        ah = __builtin_amdgcn_mfma_f32_16x16x32_f16(a0h, b0l, ah, 0, 0, 0);
        ah = __builtin_amdgcn_mfma_f32_16x16x32_f16(a1h, b1l, ah, 0, 0, 0);
        ah = __builtin_amdgcn_mfma_f32_16x16x32_f16(a0l, b0h, ah, 0, 0, 0);
        ah = __builtin_amdgcn_mfma_f32_16x16x32_f16(a1l, b1h, ah, 0, 0, 0);
#pragma unroll
        for (int g = 0; g < 16; ++g)
            accg[g] += th_pre[g * 16 + h] * ah;
    }
    const int orow = it + (l >> 4) * 4;
    const int col = jt + lr;
#pragma unroll
    for (int ph = 0; ph < 2; ++ph) {
        __syncthreads();
#pragma unroll
        for (int g = 0; g < 8; ++g)
            *(f32x4*)&red[w][g][l * 4] = accg[ph * 8 + g];
        __syncthreads();
#pragma unroll
        for (int gq = 0; gq < 2; ++gq) {
            const int gl = w * 2 + gq;
            f32x4 s = *(const f32x4*)&red[0][gl][l * 4];
            s += *(const f32x4*)&red[1][gl][l * 4];
            s += *(const f32x4*)&red[2][gl][l * 4];
            s += *(const f32x4*)&red[3][gl][l * 4];
            const int g = ph * 8 + gl;
#pragma unroll
            for (int r = 0; r < 4; ++r)
                D[((size_t)(orow + r) * 16 + g) * JPAD + col] = s[r];
        }
    }
}

// ---- exact top-k (ballot radix) + softmax; writes NORMALIZED f16 E ---------
// One row (i,h) per wave, 4 rows/block, grid 16*NQC/4 = high occupancy.
// E layout [i][h][j] (row r = i*16+h, stride JPAD); pad columns get 0.
__global__ __launch_bounds__(256) void estats_kernel(
    const float* __restrict__ D, u16* __restrict__ E)
{
    const int w = threadIdx.x >> 6, l = threadIdx.x & 63;
    const int r = blockIdx.x * 4 + w;
    const float* Dr = D + (size_t)r * JPAD;
    float v[33]; unsigned ku[33];
#pragma unroll
    for (int s = 0; s < 33; ++s) {
        int j = s * 64 + l;
        float x = (j < JTOT) ? Dr[j] : -3.0e38f;
        v[s] = x;
        unsigned u = __float_as_uint(x);
        ku[s] = (j < JTOT) ? ((u & 0x80000000u) ? ~u : (u | 0x80000000u)) : 0u;
    }
    unsigned t = 0;
    for (int b = 31; b >= 0; --b) {
        unsigned tc = t | (1u << b);
        int c = 0;
#pragma unroll
        for (int s = 0; s < 33; ++s)
            c += (int)__popcll(__ballot(ku[s] >= tc));
        if (c >= KTOP) t = tc;
    }
    float mx = v[0];
#pragma unroll
    for (int s = 1; s < 33; ++s) mx = fmaxf(mx, v[s]);
#pragma unroll
    for (int m = 32; m; m >>= 1) mx = fmaxf(mx, __shfl_xor(mx, m));
    float den = 0.0f;
#pragma unroll
    for (int s = 0; s < 33; ++s) {
        float ev = (ku[s] >= t) ? __expf(v[s] - mx) : 0.0f;
        v[s] = ev; den += ev;
    }
#pragma unroll
    for (int m = 32; m; m >>= 1) den += __shfl_xor(den, m);
    float inv = 1.0f / den;
    u16* Er = E + (size_t)r * JPAD;
#pragma unroll
    for (int s = 0; s < 33; ++s)
        Er[s * 64 + l] = f2h(v[s] * inv);
}

// ---- th_post head-mix via MFMA: P[i][g][j] = sum_h th_post[g,h] E[i][h][j].
// A-frag = th_post zero-padded to K=32 (validated layout). Grid NQC x 4.
__global__ __launch_bounds__(256) void mixp_kernel(
    const u16* __restrict__ E, const float* __restrict__ th_post,
    u16* __restrict__ P)
{
    const int tid = threadIdx.x, l = tid & 63, w = tid >> 6;
    const int i = blockIdx.x, by = blockIdx.y;
    const int g = l & 15, hg = l >> 4, hb = (hg & 1) * 8;
    f16x8 afr;
#pragma unroll
    for (int idx = 0; idx < 8; ++idx) {
        int k = hg * 8 + idx;
        afr[idx] = (_Float16)((k < 16) ? th_post[g * 16 + k] : 0.0f);
    }
    const u16* Eb = E + (size_t)i * 16 * JPAD;
    u16* Pb = P + (size_t)i * 16 * JPAD;
    for (int t = by * 4 + w; t < 129; t += 16) {
        const int j = t * 16 + g;
        f16x8 bfr;
#pragma unroll
        for (int idx = 0; idx < 8; ++idx) {
            u16 raw = Eb[(size_t)(hb + idx) * JPAD + j];
            _Float16 hv; __builtin_memcpy(&hv, &raw, 2);
            bfr[idx] = hv;
        }
        f32x4 c = {};
        c = __builtin_amdgcn_mfma_f32_16x16x32_f16(afr, bfr, c, 0, 0, 0);
#pragma unroll
        for (int r = 0; r < 4; ++r)
            Pb[(size_t)(hg * 4 + r) * JPAD + j] = f2h(c[r]);
    }
}

// ============================================================================
extern "C" void kernel_launch(void* const* d_in, const int* in_sizes, int n_in,
                              void* d_out, int out_size, void* d_ws, size_t ws_size,
                              hipStream_t stream)
{
    (void)in_sizes; (void)n_in; (void)out_size;
    const float* x      = (const float*)d_in[0];
    const float* ctx    = (const float*)d_in[1];
    const float* Wq1    = (const float*)d_in[4];
    const float* Wk1    = (const float*)d_in[5];
    const float* Wv1    = (const float*)d_in[6];
    const float* Wq2    = (const float*)d_in[7];
    const float* Wk2    = (const float*)d_in[8];
    const float* Wv2    = (const float*)d_in[9];
    const float* thpre1 = (const float*)d_in[10];
    const float* thpost1= (const float*)d_in[11];
    const float* thpre2 = (const float*)d_in[12];
    const float* thpost2= (const float*)d_in[13];
    const float* memk1  = (const float*)d_in[14];
    const float* memv1  = (const float*)d_in[15];
    const float* memk2  = (const float*)d_in[16];
    const float* memv2  = (const float*)d_in[17];
    const float* sc1    = (const float*)d_in[18];
    const float* sc2    = (const float*)d_in[19];
    const float* hs1    = (const float*)d_in[20];
    const float* hs2    = (const float*)d_in[21];
    const float* Wo1    = (const float*)d_in[22];
    const float* Wo2    = (const float*)d_in[23];

    char* p = (char*)d_ws;
    auto alloc = [&](size_t n) { char* r = p; p += (n + 255) & ~(size_t)255; return r; };
    u16*   xbh   = (u16*)alloc((size_t)NQ * DIMM * 2);
    u16*   xbl   = (u16*)alloc((size_t)NQ * DIMM * 2);
    u16*   cb0h  = (u16*)alloc((size_t)NQ * DIMM * 2);
    u16*   cb0l  = (u16*)alloc((size_t)NQ * DIMM * 2);
    u16*   cb1h  = (u16*)alloc((size_t)NQ * DIMM * 2);
    u16*   cb1l  = (u16*)alloc((size_t)NQ * DIMM * 2);
    u16*   WTh   = (u16*)alloc((size_t)8 * DIMM * DIMM * 2);
    u16*   WTl   = (u16*)alloc((size_t)8 * DIMM * DIMM * 2);
    float* Qf    = (float*)alloc((size_t)NQ * DIMM * 4);   // also reused as x2f
    float* Kf    = (float*)alloc((size_t)NQ * DIMM * 4);
    float* Vf    = (float*)alloc((size_t)NQ * DIMM * 4);
    u16*   qnh   = (u16*)alloc((size_t)16 * NQ * 64 * 2);
    u16*   qnl   = (u16*)alloc((size_t)16 * NQ * 64 * 2);
    u16*   knh   = (u16*)alloc((size_t)16 * JPK * 64 * 2);
    u16*   knl   = (u16*)alloc((size_t)16 * JPK * 64 * 2);
    u16*   vvT   = (u16*)alloc((size_t)16 * 64 * JPAD * 2);
    u16*   attnA = (u16*)alloc((size_t)NQ * DIMM * 2);
    size_t used = (size_t)(p - (char*)d_ws);

    int NQC = 32;
    for (int cand : {512, 256, 128, 64}) {
        if (used + (size_t)16 * cand * JPAD * 8 + 1024 <= ws_size) { NQC = cand; break; }
    }
    float* Dbuf = (float*)alloc((size_t)16 * NQC * JPAD * 4);
    u16*   Ebuf = (u16*)alloc((size_t)16 * NQC * JPAD * 2);
    u16*   Pbuf = (u16*)alloc((size_t)16 * NQC * JPAD * 2);

    // ---- one-time split-casts ----
    const int N4 = (NQ * DIMM) / 4;
    split1_kernel<<<2048, 256, 0, stream>>>(x, xbh, xbl, N4);
    split1_kernel<<<2048, 256, 0, stream>>>(ctx, cb0h, cb0l, N4);
    split1_kernel<<<2048, 256, 0, stream>>>(ctx + (size_t)NQ * DIMM, cb1h, cb1l, N4);
    P8 w8{ { Wq1, Wk1, Wv1, Wo1, Wq2, Wk2, Wv2, Wo2 } };
    wtrans_kernel<<<dim3(16, 16, 8), 256, 0, stream>>>(w8, WTh, WTl);

    auto layer = [&](const u16* inh, const u16* inl,
                     const u16* ctxh, const u16* ctxl, int wbase,
                     const float* thpre, const float* thpost,
                     const float* memk, const float* memv,
                     const float* scp, const float* hsp, int li) {
        size_t o_q = (size_t)(wbase + 0) * DIMM * DIMM;
        size_t o_k = (size_t)(wbase + 1) * DIMM * DIMM;
        size_t o_v = (size_t)(wbase + 2) * DIMM * DIMM;
        size_t o_o = (size_t)(wbase + 3) * DIMM * DIMM;
        gemm3_nt<<<dim3(32, 16), 256, 0, stream>>>(inh, inl, DIMM, WTh + o_q, WTl + o_q, DIMM, Qf, DIMM, DIMM);
        gemm3_nt<<<dim3(32, 16), 256, 0, stream>>>(ctxh, ctxl, DIMM, WTh + o_k, WTl + o_k, DIMM, Kf, DIMM, DIMM);
        gemm_nt<0><<<dim3(32, 16, 1), 256, 0, stream>>>(ctxh, DIMM, 0, WTh + o_v, DIMM, 0, Vf, DIMM, 0, DIMM);
        normq_kernel<<<(16 * NQ) / 4, 256, 0, stream>>>(Qf, scp, qnh, qnl);
        buildkn_kernel<<<(16 * JPK) / 4, 256, 0, stream>>>(Kf, memk, knh, knl);
        buildvvT_kernel<<<dim3(33, 1, 16), 256, 0, stream>>>(Vf, memv, hsp, vvT);
        int nch = NQ / NQC;
        for (int c = 0; c < nch; ++c) {
            int q0 = c * NQC;
            dots_kernel<<<dim3(NQC / 16, JTOT / 16), 256, 0, stream>>>(qnh, qnl, knh, knl, thpre, Dbuf, q0, NQC);
            estats_kernel<<<(16 * NQC) / 4, 256, 0, stream>>>(Dbuf, Ebuf);
            mixp_kernel<<<dim3(NQC, 4), 256, 0, stream>>>(Ebuf, thpost, Pbuf);
            gemm_nt<1><<<dim3(NQC / 64, 1, 16), 256, 0, stream>>>(
                Pbuf, 16 * JPAD, (long)JPAD, vvT, JPAD, (long)64 * JPAD,
                attnA + (size_t)q0 * DIMM, DIMM, 64, JPAD);
        }
        if (li == 0) {
            // f32 layer-1 output into Qf (dead here), then split for layer 2
            gemm_nt<0><<<dim3(32, 16, 1), 256, 0, stream>>>(attnA, DIMM, 0, WTh + o_o, DIMM, 0, Qf, DIMM, 0, DIMM);
            split1_kernel<<<2048, 256, 0, stream>>>(Qf, xbh, xbl, N4);
        } else {
            gemm_nt<0><<<dim3(32, 16, 1), 256, 0, stream>>>(attnA, DIMM, 0, WTh + o_o, DIMM, 0, d_out, DIMM, 0, DIMM);
        }
    };

    layer(xbh, xbl, cb0h, cb0l, 0, thpre1, thpost1, memk1, memv1, sc1, hs1, 0);
    layer(xbh, xbl, cb1h, cb1l, 4, thpre2, thpost2, memk2, memv2, sc2, hs2, 1);
}